// Round 1
// baseline (6976.527 us; speedup 1.0000x reference)
//
#include <hip/hip_runtime.h>
#include <cstddef>

#define TPB 256

__global__ void deg_kernel(const int* __restrict__ col, const float* __restrict__ w,
                           float* __restrict__ deg, int E) {
  int t = blockIdx.x * blockDim.x + threadIdx.x;
  if (t < E) atomicAdd(&deg[col[t]], w[t]);
}

__global__ void dinv_kernel(const float* __restrict__ deg, float* __restrict__ dinv, int n) {
  int t = blockIdx.x * blockDim.x + threadIdx.x;
  if (t < n) dinv[t] = rsqrtf(deg[t] + 1.0f);  // +1 = self-loop weight
}

__global__ void norm_kernel(const int* __restrict__ row, const int* __restrict__ col,
                            const float* __restrict__ w, const float* __restrict__ dinv,
                            float* __restrict__ nrm, int E) {
  int t = blockIdx.x * blockDim.x + threadIdx.x;
  if (t < E) nrm[t] = dinv[row[t]] * w[t] * dinv[col[t]];
}

__global__ void bn_prep_kernel(const float* g1, const float* be1, const float* rm1, const float* rv1,
                               const float* g2, const float* be2, const float* rm2, const float* rv2,
                               float* sc1, float* sh1, float* sc2, float* sh2) {
  int t = threadIdx.x;
  if (t < 128) {
    float s1 = g1[t] * rsqrtf(rv1[t] + 1e-5f);
    sc1[t] = s1; sh1[t] = be1[t] - rm1[t] * s1;
    float s2 = g2[t] * rsqrtf(rv2[t] + 1e-5f);
    sc2[t] = s2; sh2[t] = be2[t] - rm2[t] * s2;
  }
}

// X[N,128] @ W[128,DOUT] -> XW (ld=128). Also writes H = XW*dinv^2 + bias
// (self-loop + bias init for the scatter accumulator).
// BN+ReLU applied to X while staging (for layers 2,3).
// NOTE: X and H may alias (same rows, read-before-write separated by barriers),
// so no __restrict__ on them.
template<int DOUT, bool BN>
__global__ __launch_bounds__(256) void gemm_kernel(
    const float* X, const float* __restrict__ W,
    const float* __restrict__ bias,
    const float* __restrict__ bnsc, const float* __restrict__ bnsh,
    const float* __restrict__ dinv,
    float* __restrict__ XW, float* H, int n)
{
  constexpr int CG  = DOUT / 4;   // col groups of 4
  constexpr int RG  = 256 / CG;   // row groups
  constexpr int RPT = 32 / RG;    // rows per thread
  __shared__ float Xs[32][132];   // +4 pad: rows land on distinct banks
  __shared__ float Ws[32][DOUT];
  const int tid = threadIdx.x;
  const int r0  = blockIdx.x * 32;

  // stage 32 rows of X (with optional BN+ReLU)
  for (int i = tid; i < 32 * 32; i += 256) {
    int rr = i >> 5, f4 = i & 31;
    int gr = r0 + rr;
    float4 v = make_float4(0.f, 0.f, 0.f, 0.f);
    if (gr < n) v = *(const float4*)(X + (size_t)gr * 128 + f4 * 4);
    if constexpr (BN) {
      int k = f4 * 4;
      v.x = fmaxf(fmaf(v.x, bnsc[k + 0], bnsh[k + 0]), 0.f);
      v.y = fmaxf(fmaf(v.y, bnsc[k + 1], bnsh[k + 1]), 0.f);
      v.z = fmaxf(fmaf(v.z, bnsc[k + 2], bnsh[k + 2]), 0.f);
      v.w = fmaxf(fmaf(v.w, bnsc[k + 3], bnsh[k + 3]), 0.f);
    }
    *(float4*)(&Xs[rr][f4 * 4]) = v;   // 132*4=528 bytes/row, 16B-aligned
  }

  float acc[RPT][4];
#pragma unroll
  for (int i = 0; i < RPT; ++i)
    acc[i][0] = acc[i][1] = acc[i][2] = acc[i][3] = 0.f;

  const int rg = tid / CG;
  const int cg = tid % CG;

  for (int kk = 0; kk < 128; kk += 32) {
    __syncthreads();  // also covers initial X staging
    for (int i = tid; i < 32 * CG; i += 256) {
      int kr = i / CG, f4 = i % CG;
      *(float4*)(&Ws[kr][f4 * 4]) = *(const float4*)(W + (size_t)(kk + kr) * DOUT + f4 * 4);
    }
    __syncthreads();
#pragma unroll
    for (int k = 0; k < 32; ++k) {
      float4 wv = *(const float4*)(&Ws[k][cg * 4]);
#pragma unroll
      for (int i = 0; i < RPT; ++i) {
        float a = Xs[rg * RPT + i][kk + k];
        acc[i][0] = fmaf(a, wv.x, acc[i][0]);
        acc[i][1] = fmaf(a, wv.y, acc[i][1]);
        acc[i][2] = fmaf(a, wv.z, acc[i][2]);
        acc[i][3] = fmaf(a, wv.w, acc[i][3]);
      }
    }
  }

#pragma unroll
  for (int i = 0; i < RPT; ++i) {
    int gr = r0 + rg * RPT + i;
    if (gr < n) {
      float dv  = dinv[gr];
      float dv2 = dv * dv;
      float4 o;
      o.x = acc[i][0]; o.y = acc[i][1]; o.z = acc[i][2]; o.w = acc[i][3];
      *(float4*)(XW + (size_t)gr * 128 + cg * 4) = o;
      float4 hh;
      hh.x = fmaf(o.x, dv2, bias[cg * 4 + 0]);
      hh.y = fmaf(o.y, dv2, bias[cg * 4 + 1]);
      hh.z = fmaf(o.z, dv2, bias[cg * 4 + 2]);
      hh.w = fmaf(o.w, dv2, bias[cg * 4 + 3]);
      *(float4*)(H + (size_t)gr * 128 + cg * 4) = hh;
    }
  }
}

// h[col[e]] += xw[row[e]] * norm[e]  (push / atomic formulation)
template<int CHUNKS>  // D/4
__global__ void scatter_kernel(const int* __restrict__ row, const int* __restrict__ col,
                               const float* __restrict__ nrm, const float* __restrict__ xw,
                               float* __restrict__ h, int E)
{
  int t = blockIdx.x * blockDim.x + threadIdx.x;
  int e = t / CHUNKS;
  if (e >= E) return;
  int c = t % CHUNKS;
  int r = row[e], cl = col[e];
  float nm = nrm[e];
  float4 v = *(const float4*)(xw + (size_t)r * 128 + c * 4);
  float* dst = h + (size_t)cl * 128 + c * 4;
  atomicAdd(dst + 0, v.x * nm);
  atomicAdd(dst + 1, v.y * nm);
  atomicAdd(dst + 2, v.z * nm);
  atomicAdd(dst + 3, v.w * nm);
}

// out[i] = h[i,0:64] / max(||h[i,0:64]||, 1e-12); one 64-lane wave per row
__global__ void normalize_kernel(const float* __restrict__ h, float* __restrict__ out, int n) {
  int t = blockIdx.x * blockDim.x + threadIdx.x;
  int i = t >> 6;
  int d = t & 63;
  if (i >= n) return;
  float v = h[(size_t)i * 128 + d];
  float s = v * v;
#pragma unroll
  for (int off = 32; off >= 1; off >>= 1) s += __shfl_xor(s, off);
  float scale = 1.0f / fmaxf(sqrtf(s), 1e-12f);
  out[(size_t)i * 64 + d] = v * scale;
}

extern "C" void kernel_launch(void* const* d_in, const int* in_sizes, int n_in,
                              void* d_out, int out_size, void* d_ws, size_t ws_size,
                              hipStream_t stream)
{
  const float* x   = (const float*)d_in[0];
  const int*   ei  = (const int*)d_in[1];
  const float* ew  = (const float*)d_in[2];
  const float* W1  = (const float*)d_in[3];
  const float* b1  = (const float*)d_in[4];
  const float* g1  = (const float*)d_in[5];
  const float* be1 = (const float*)d_in[6];
  const float* rm1 = (const float*)d_in[7];
  const float* rv1 = (const float*)d_in[8];
  const float* W2  = (const float*)d_in[9];
  const float* b2  = (const float*)d_in[10];
  const float* g2  = (const float*)d_in[11];
  const float* be2 = (const float*)d_in[12];
  const float* rm2 = (const float*)d_in[13];
  const float* rv2 = (const float*)d_in[14];
  const float* W3  = (const float*)d_in[15];
  const float* b3  = (const float*)d_in[16];

  const int N = in_sizes[0] / 128;
  const int E = in_sizes[2];
  const int* row = ei;       // edge_index[0]
  const int* col = ei + E;   // edge_index[1]

  char* ws = (char*)d_ws;
  size_t off = 0;
  auto alloc = [&](size_t bytes) -> void* {
    void* p = ws + off;
    off += (bytes + 255) & ~(size_t)255;
    return p;
  };
  float* deg  = (float*)alloc((size_t)N * 4);
  float* dinv = (float*)alloc((size_t)N * 4);
  float* nrm  = (float*)alloc((size_t)E * 4);
  float* sc1  = (float*)alloc(512);
  float* sh1  = (float*)alloc(512);
  float* sc2  = (float*)alloc(512);
  float* sh2  = (float*)alloc(512);
  float* xw   = (float*)alloc((size_t)N * 128 * 4);
  float* h    = (float*)alloc((size_t)N * 128 * 4);

  hipMemsetAsync(deg, 0, (size_t)N * 4, stream);

  int gE = (E + TPB - 1) / TPB;
  int gN = (N + TPB - 1) / TPB;
  deg_kernel<<<gE, TPB, 0, stream>>>(col, ew, deg, E);
  dinv_kernel<<<gN, TPB, 0, stream>>>(deg, dinv, N);
  norm_kernel<<<gE, TPB, 0, stream>>>(row, col, ew, dinv, nrm, E);
  bn_prep_kernel<<<1, 128, 0, stream>>>(g1, be1, rm1, rv1, g2, be2, rm2, rv2,
                                        sc1, sh1, sc2, sh2);

  int gG = (N + 31) / 32;
  int gS32 = (int)(((size_t)E * 32 + TPB - 1) / TPB);
  int gS16 = (int)(((size_t)E * 16 + TPB - 1) / TPB);

  // layer 1
  gemm_kernel<128, false><<<gG, 256, 0, stream>>>(x, W1, b1, nullptr, nullptr, dinv, xw, h, N);
  scatter_kernel<32><<<gS32, TPB, 0, stream>>>(row, col, nrm, xw, h, E);

  // layer 2 (BN1+ReLU fused into X staging; h read+re-init is row-owned, safe)
  gemm_kernel<128, true><<<gG, 256, 0, stream>>>(h, W2, b2, sc1, sh1, dinv, xw, h, N);
  scatter_kernel<32><<<gS32, TPB, 0, stream>>>(row, col, nrm, xw, h, E);

  // layer 3 (BN2+ReLU fused; DOUT=64, ld stays 128)
  gemm_kernel<64, true><<<gG, 256, 0, stream>>>(h, W3, b3, sc2, sh2, dinv, xw, h, N);
  scatter_kernel<16><<<gS16, TPB, 0, stream>>>(row, col, nrm, xw, h, E);

  normalize_kernel<<<((size_t)N * 64 + TPB - 1) / TPB, TPB, 0, stream>>>(h, (float*)d_out, N);
}

// Round 2
// 931.895 us; speedup vs baseline: 7.4864x; 7.4864x over previous
//
#include <hip/hip_runtime.h>
#include <cstddef>

#define TPB 256

// deg[c] += w ; cnt[c] += 1  (histogram for CSR)
__global__ void deg_kernel(const int* __restrict__ col, const float* __restrict__ w,
                           float* __restrict__ deg, int* __restrict__ cnt, int E) {
  int t = blockIdx.x * blockDim.x + threadIdx.x;
  if (t < E) {
    int c = col[t];
    atomicAdd(&deg[c], w[t]);
    atomicAdd(&cnt[c], 1);
  }
}

__global__ void dinv_kernel(const float* __restrict__ deg, float* __restrict__ dinv, int n) {
  int t = blockIdx.x * blockDim.x + threadIdx.x;
  if (t < n) dinv[t] = rsqrtf(deg[t] + 1.0f);  // +1 = self-loop weight
}

// single-block exclusive scan of cnt[n] -> rowptr[n+1]
__global__ __launch_bounds__(1024) void scan_kernel(const int* __restrict__ cnt,
                                                    int* __restrict__ rowptr, int n) {
  __shared__ int sums[1024];
  const int tid = threadIdx.x;
  const int per = (n + 1023) / 1024;
  const int base = tid * per;
  int s = 0;
  for (int i = 0; i < per; ++i) {
    int idx = base + i;
    if (idx < n) s += cnt[idx];
  }
  sums[tid] = s;
  __syncthreads();
  for (int off = 1; off < 1024; off <<= 1) {
    int t = (tid >= off) ? sums[tid - off] : 0;
    __syncthreads();
    sums[tid] += t;
    __syncthreads();
  }
  int running = sums[tid] - s;  // exclusive prefix of this thread's chunk
  for (int i = 0; i < per; ++i) {
    int idx = base + i;
    if (idx < n) { rowptr[idx] = running; running += cnt[idx]; }
  }
  if (tid == 1023) rowptr[n] = sums[1023];
}

// csr[rowptr[col[e]] + pos] = (row[e], norm[e]); norm computed inline
__global__ void fill_kernel(const int* __restrict__ row, const int* __restrict__ col,
                            const float* __restrict__ w, const float* __restrict__ dinv,
                            const int* __restrict__ rowptr, int* __restrict__ cursor,
                            int2* __restrict__ csr, int E) {
  int e = blockIdx.x * blockDim.x + threadIdx.x;
  if (e >= E) return;
  int r = row[e], c = col[e];
  float nm = dinv[r] * w[e] * dinv[c];
  int pos = atomicAdd(&cursor[c], 1);
  csr[rowptr[c] + pos] = make_int2(r, __float_as_int(nm));
}

__global__ void bn_prep_kernel(const float* g1, const float* be1, const float* rm1, const float* rv1,
                               const float* g2, const float* be2, const float* rm2, const float* rv2,
                               float* sc1, float* sh1, float* sc2, float* sh2) {
  int t = threadIdx.x;
  if (t < 128) {
    float s1 = g1[t] * rsqrtf(rv1[t] + 1e-5f);
    sc1[t] = s1; sh1[t] = be1[t] - rm1[t] * s1;
    float s2 = g2[t] * rsqrtf(rv2[t] + 1e-5f);
    sc2[t] = s2; sh2[t] = be2[t] - rm2[t] * s2;
  }
}

// X[N,128] @ W[128,DOUT] -> XW (ld=128). BN+ReLU fused into X staging.
template<int DOUT, bool BN>
__global__ __launch_bounds__(256) void gemm_kernel(
    const float* __restrict__ X, const float* __restrict__ W,
    const float* __restrict__ bnsc, const float* __restrict__ bnsh,
    float* __restrict__ XW, int n)
{
  constexpr int CG  = DOUT / 4;   // col groups of 4
  constexpr int RG  = 256 / CG;   // row groups
  constexpr int RPT = 32 / RG;    // rows per thread
  __shared__ float Xs[32][132];   // +4 pad
  __shared__ float Ws[32][DOUT];
  const int tid = threadIdx.x;
  const int r0  = blockIdx.x * 32;

  for (int i = tid; i < 32 * 32; i += 256) {
    int rr = i >> 5, f4 = i & 31;
    int gr = r0 + rr;
    float4 v = make_float4(0.f, 0.f, 0.f, 0.f);
    if (gr < n) v = *(const float4*)(X + (size_t)gr * 128 + f4 * 4);
    if constexpr (BN) {
      int k = f4 * 4;
      v.x = fmaxf(fmaf(v.x, bnsc[k + 0], bnsh[k + 0]), 0.f);
      v.y = fmaxf(fmaf(v.y, bnsc[k + 1], bnsh[k + 1]), 0.f);
      v.z = fmaxf(fmaf(v.z, bnsc[k + 2], bnsh[k + 2]), 0.f);
      v.w = fmaxf(fmaf(v.w, bnsc[k + 3], bnsh[k + 3]), 0.f);
    }
    *(float4*)(&Xs[rr][f4 * 4]) = v;
  }

  float acc[RPT][4];
#pragma unroll
  for (int i = 0; i < RPT; ++i)
    acc[i][0] = acc[i][1] = acc[i][2] = acc[i][3] = 0.f;

  const int rg = tid / CG;
  const int cg = tid % CG;

  for (int kk = 0; kk < 128; kk += 32) {
    __syncthreads();
    for (int i = tid; i < 32 * CG; i += 256) {
      int kr = i / CG, f4 = i % CG;
      *(float4*)(&Ws[kr][f4 * 4]) = *(const float4*)(W + (size_t)(kk + kr) * DOUT + f4 * 4);
    }
    __syncthreads();
#pragma unroll
    for (int k = 0; k < 32; ++k) {
      float4 wv = *(const float4*)(&Ws[k][cg * 4]);
#pragma unroll
      for (int i = 0; i < RPT; ++i) {
        float a = Xs[rg * RPT + i][kk + k];
        acc[i][0] = fmaf(a, wv.x, acc[i][0]);
        acc[i][1] = fmaf(a, wv.y, acc[i][1]);
        acc[i][2] = fmaf(a, wv.z, acc[i][2]);
        acc[i][3] = fmaf(a, wv.w, acc[i][3]);
      }
    }
  }

#pragma unroll
  for (int i = 0; i < RPT; ++i) {
    int gr = r0 + rg * RPT + i;
    if (gr < n) {
      float4 o;
      o.x = acc[i][0]; o.y = acc[i][1]; o.z = acc[i][2]; o.w = acc[i][3];
      *(float4*)(XW + (size_t)gr * 128 + cg * 4) = o;
    }
  }
}

// pull-gather: h[i] = bias + dinv[i]^2 * xw[i] + sum_e nrm[e] * xw[row_e]
// one 64-lane wave per node. FINAL: D=64, fuse L2-normalize, write d_out.
template<int D, bool FINAL>
__global__ __launch_bounds__(256) void gather_kernel(
    const int* __restrict__ rowptr, const int2* __restrict__ csr,
    const float* __restrict__ xw, const float* __restrict__ dinv,
    const float* __restrict__ bias, float* __restrict__ out, int n)
{
  int wid  = (blockIdx.x * blockDim.x + threadIdx.x) >> 6;
  int lane = threadIdx.x & 63;
  if (wid >= n) return;
  const int start = rowptr[wid];
  const int end   = rowptr[wid + 1];
  const float dv  = dinv[wid];
  const float dv2 = dv * dv;

  if constexpr (!FINAL) {
    // D=128: float2 per lane
    const size_t c0 = (size_t)lane * 2;
    float2 self = *(const float2*)(xw + (size_t)wid * 128 + c0);
    float a0 = fmaf(self.x, dv2, bias[c0]);
    float a1 = fmaf(self.y, dv2, bias[c0 + 1]);
    int e = start;
    for (; e + 1 < end; e += 2) {
      int2 p0 = csr[e];
      int2 p1 = csr[e + 1];
      float2 v0 = *(const float2*)(xw + (size_t)p0.x * 128 + c0);
      float2 v1 = *(const float2*)(xw + (size_t)p1.x * 128 + c0);
      float n0 = __int_as_float(p0.y), n1 = __int_as_float(p1.y);
      a0 = fmaf(v0.x, n0, a0); a1 = fmaf(v0.y, n0, a1);
      a0 = fmaf(v1.x, n1, a0); a1 = fmaf(v1.y, n1, a1);
    }
    if (e < end) {
      int2 p0 = csr[e];
      float2 v0 = *(const float2*)(xw + (size_t)p0.x * 128 + c0);
      float n0 = __int_as_float(p0.y);
      a0 = fmaf(v0.x, n0, a0); a1 = fmaf(v0.y, n0, a1);
    }
    *(float2*)(out + (size_t)wid * 128 + c0) = make_float2(a0, a1);
  } else {
    // D=64 (xw ld=128): one float per lane, fused row-normalize
    float self = xw[(size_t)wid * 128 + lane];
    float a = fmaf(self, dv2, bias[lane]);
    int e = start;
    for (; e + 1 < end; e += 2) {
      int2 p0 = csr[e];
      int2 p1 = csr[e + 1];
      float v0 = xw[(size_t)p0.x * 128 + lane];
      float v1 = xw[(size_t)p1.x * 128 + lane];
      a = fmaf(v0, __int_as_float(p0.y), a);
      a = fmaf(v1, __int_as_float(p1.y), a);
    }
    if (e < end) {
      int2 p0 = csr[e];
      float v0 = xw[(size_t)p0.x * 128 + lane];
      a = fmaf(v0, __int_as_float(p0.y), a);
    }
    float s = a * a;
#pragma unroll
    for (int off = 32; off >= 1; off >>= 1) s += __shfl_xor(s, off);
    float scale = 1.0f / fmaxf(sqrtf(s), 1e-12f);
    out[(size_t)wid * 64 + lane] = a * scale;
  }
}

extern "C" void kernel_launch(void* const* d_in, const int* in_sizes, int n_in,
                              void* d_out, int out_size, void* d_ws, size_t ws_size,
                              hipStream_t stream)
{
  const float* x   = (const float*)d_in[0];
  const int*   ei  = (const int*)d_in[1];
  const float* ew  = (const float*)d_in[2];
  const float* W1  = (const float*)d_in[3];
  const float* b1  = (const float*)d_in[4];
  const float* g1  = (const float*)d_in[5];
  const float* be1 = (const float*)d_in[6];
  const float* rm1 = (const float*)d_in[7];
  const float* rv1 = (const float*)d_in[8];
  const float* W2  = (const float*)d_in[9];
  const float* b2  = (const float*)d_in[10];
  const float* g2  = (const float*)d_in[11];
  const float* be2 = (const float*)d_in[12];
  const float* rm2 = (const float*)d_in[13];
  const float* rv2 = (const float*)d_in[14];
  const float* W3  = (const float*)d_in[15];
  const float* b3  = (const float*)d_in[16];

  const int N = in_sizes[0] / 128;
  const int E = in_sizes[2];
  const int* row = ei;       // edge_index[0]
  const int* col = ei + E;   // edge_index[1]

  char* ws = (char*)d_ws;
  size_t off = 0;
  auto alloc = [&](size_t bytes) -> void* {
    void* p = ws + off;
    off += (bytes + 255) & ~(size_t)255;
    return p;
  };
  float* deg    = (float*)alloc((size_t)N * 4);
  int*   cnt    = (int*)  alloc((size_t)N * 4);
  int*   cursor = (int*)  alloc((size_t)N * 4);
  float* dinv   = (float*)alloc((size_t)N * 4);
  int*   rowptr = (int*)  alloc((size_t)(N + 1) * 4);
  int2*  csr    = (int2*) alloc((size_t)E * 8);
  float* sc1    = (float*)alloc(512);
  float* sh1    = (float*)alloc(512);
  float* sc2    = (float*)alloc(512);
  float* sh2    = (float*)alloc(512);
  float* xw     = (float*)alloc((size_t)N * 128 * 4);
  float* h      = (float*)alloc((size_t)N * 128 * 4);

  hipMemsetAsync(deg, 0, (size_t)N * 4, stream);
  hipMemsetAsync(cnt, 0, (size_t)N * 4, stream);
  hipMemsetAsync(cursor, 0, (size_t)N * 4, stream);

  int gE = (E + TPB - 1) / TPB;
  int gN = (N + TPB - 1) / TPB;
  deg_kernel<<<gE, TPB, 0, stream>>>(col, ew, deg, cnt, E);
  dinv_kernel<<<gN, TPB, 0, stream>>>(deg, dinv, N);
  scan_kernel<<<1, 1024, 0, stream>>>(cnt, rowptr, N);
  fill_kernel<<<gE, TPB, 0, stream>>>(row, col, ew, dinv, rowptr, cursor, csr, E);
  bn_prep_kernel<<<1, 128, 0, stream>>>(g1, be1, rm1, rv1, g2, be2, rm2, rv2,
                                        sc1, sh1, sc2, sh2);

  const int gG  = (N + 31) / 32;       // gemm blocks
  const int gW  = (N + 3) / 4;         // gather blocks (4 waves/block)

  // layer 1
  gemm_kernel<128, false><<<gG, 256, 0, stream>>>(x, W1, nullptr, nullptr, xw, N);
  gather_kernel<128, false><<<gW, 256, 0, stream>>>(rowptr, csr, xw, dinv, b1, h, N);

  // layer 2
  gemm_kernel<128, true><<<gG, 256, 0, stream>>>(h, W2, sc1, sh1, xw, N);
  gather_kernel<128, false><<<gW, 256, 0, stream>>>(rowptr, csr, xw, dinv, b2, h, N);

  // layer 3 (DOUT=64, xw ld stays 128) + fused L2 normalize -> d_out
  gemm_kernel<64, true><<<gG, 256, 0, stream>>>(h, W3, sc2, sh2, xw, N);
  gather_kernel<64, true><<<gW, 256, 0, stream>>>(rowptr, csr, xw, dinv, b3, (float*)d_out, N);
}

// Round 3
// 719.809 us; speedup vs baseline: 9.6922x; 1.2946x over previous
//
#include <hip/hip_runtime.h>
#include <cstddef>

#define TPB 256

// deg[c] += w ; cnt[c] += 1  (histogram for CSR)
__global__ void deg_kernel(const int* __restrict__ col, const float* __restrict__ w,
                           float* __restrict__ deg, int* __restrict__ cnt, int E) {
  int t = blockIdx.x * blockDim.x + threadIdx.x;
  if (t < E) {
    int c = col[t];
    atomicAdd(&deg[c], w[t]);
    atomicAdd(&cnt[c], 1);
  }
}

__global__ void dinv_kernel(const float* __restrict__ deg, float* __restrict__ dinv, int n) {
  int t = blockIdx.x * blockDim.x + threadIdx.x;
  if (t < n) dinv[t] = rsqrtf(deg[t] + 1.0f);  // +1 = self-loop weight
}

// ---- hierarchical scan: cnt[n] -> rowptr[n+1] (exclusive) ----
// pass 1: per-block (1024 elems) totals
__global__ __launch_bounds__(256) void scan_partial(const int* __restrict__ cnt,
                                                    int* __restrict__ bsum, int n) {
  __shared__ int red[256];
  const int b = blockIdx.x, tid = threadIdx.x;
  const int base = b * 1024 + tid * 4;
  int s = 0;
  if (base + 3 < n) {
    int4 v = *(const int4*)(cnt + base);
    s = v.x + v.y + v.z + v.w;
  } else {
    for (int j = 0; j < 4; ++j) if (base + j < n) s += cnt[base + j];
  }
  red[tid] = s; __syncthreads();
  for (int off = 128; off >= 1; off >>= 1) {
    if (tid < off) red[tid] += red[tid + off];
    __syncthreads();
  }
  if (tid == 0) bsum[b] = red[0];
}

// pass 2: exclusive scan of block sums (single block, nb <= 1024) + rowptr[n] = total
__global__ __launch_bounds__(1024) void scan_bsum(int* __restrict__ bsum, int nb,
                                                  int* __restrict__ rowptr, int n) {
  __shared__ int sh[1024];
  const int tid = threadIdx.x;
  int v = (tid < nb) ? bsum[tid] : 0;
  sh[tid] = v; __syncthreads();
  for (int off = 1; off < 1024; off <<= 1) {
    int t = (tid >= off) ? sh[tid - off] : 0;
    __syncthreads();
    sh[tid] += t;
    __syncthreads();
  }
  if (tid < nb) bsum[tid] = sh[tid] - v;   // exclusive
  if (tid == 1023) rowptr[n] = sh[1023];   // grand total
}

// pass 3: local scan + block offset -> rowptr[0..n)
__global__ __launch_bounds__(256) void scan_apply(const int* __restrict__ cnt,
                                                  const int* __restrict__ bsum,
                                                  int* __restrict__ rowptr, int n) {
  __shared__ int red[256];
  const int b = blockIdx.x, tid = threadIdx.x;
  const int base = b * 1024 + tid * 4;
  int v0 = 0, v1 = 0, v2 = 0, v3 = 0;
  if (base + 3 < n) {
    int4 v = *(const int4*)(cnt + base);
    v0 = v.x; v1 = v.y; v2 = v.z; v3 = v.w;
  } else {
    if (base     < n) v0 = cnt[base];
    if (base + 1 < n) v1 = cnt[base + 1];
    if (base + 2 < n) v2 = cnt[base + 2];
    if (base + 3 < n) v3 = cnt[base + 3];
  }
  const int t = v0 + v1 + v2 + v3;
  red[tid] = t; __syncthreads();
  for (int off = 1; off < 256; off <<= 1) {
    int x = (tid >= off) ? red[tid - off] : 0;
    __syncthreads();
    red[tid] += x;
    __syncthreads();
  }
  int excl = red[tid] - t + bsum[b];
  if (base     < n) rowptr[base]     = excl;
  if (base + 1 < n) rowptr[base + 1] = excl + v0;
  if (base + 2 < n) rowptr[base + 2] = excl + v0 + v1;
  if (base + 3 < n) rowptr[base + 3] = excl + v0 + v1 + v2;
}

// csr[rowptr[col[e]] + pos] = (row[e], norm[e]); norm computed inline
__global__ void fill_kernel(const int* __restrict__ row, const int* __restrict__ col,
                            const float* __restrict__ w, const float* __restrict__ dinv,
                            const int* __restrict__ rowptr, int* __restrict__ cursor,
                            int2* __restrict__ csr, int E) {
  int e = blockIdx.x * blockDim.x + threadIdx.x;
  if (e >= E) return;
  int r = row[e], c = col[e];
  float nm = dinv[r] * w[e] * dinv[c];
  int pos = atomicAdd(&cursor[c], 1);
  csr[rowptr[c] + pos] = make_int2(r, __float_as_int(nm));
}

__global__ void bn_prep_kernel(const float* g1, const float* be1, const float* rm1, const float* rv1,
                               const float* g2, const float* be2, const float* rm2, const float* rv2,
                               float* sc1, float* sh1, float* sc2, float* sh2) {
  int t = threadIdx.x;
  if (t < 128) {
    float s1 = g1[t] * rsqrtf(rv1[t] + 1e-5f);
    sc1[t] = s1; sh1[t] = be1[t] - rm1[t] * s1;
    float s2 = g2[t] * rsqrtf(rv2[t] + 1e-5f);
    sc2[t] = s2; sh2[t] = be2[t] - rm2[t] * s2;
  }
}

// X[N,128] @ W[128,DOUT] -> XW (ld=128). BN+ReLU fused into X staging.
template<int DOUT, bool BN>
__global__ __launch_bounds__(256) void gemm_kernel(
    const float* __restrict__ X, const float* __restrict__ W,
    const float* __restrict__ bnsc, const float* __restrict__ bnsh,
    float* __restrict__ XW, int n)
{
  constexpr int CG  = DOUT / 4;   // col groups of 4
  constexpr int RG  = 256 / CG;   // row groups
  constexpr int RPT = 32 / RG;    // rows per thread
  __shared__ float Xs[32][132];   // +4 pad
  __shared__ float Ws[32][DOUT];
  const int tid = threadIdx.x;
  const int r0  = blockIdx.x * 32;

  for (int i = tid; i < 32 * 32; i += 256) {
    int rr = i >> 5, f4 = i & 31;
    int gr = r0 + rr;
    float4 v = make_float4(0.f, 0.f, 0.f, 0.f);
    if (gr < n) v = *(const float4*)(X + (size_t)gr * 128 + f4 * 4);
    if constexpr (BN) {
      int k = f4 * 4;
      v.x = fmaxf(fmaf(v.x, bnsc[k + 0], bnsh[k + 0]), 0.f);
      v.y = fmaxf(fmaf(v.y, bnsc[k + 1], bnsh[k + 1]), 0.f);
      v.z = fmaxf(fmaf(v.z, bnsc[k + 2], bnsh[k + 2]), 0.f);
      v.w = fmaxf(fmaf(v.w, bnsc[k + 3], bnsh[k + 3]), 0.f);
    }
    *(float4*)(&Xs[rr][f4 * 4]) = v;
  }

  float acc[RPT][4];
#pragma unroll
  for (int i = 0; i < RPT; ++i)
    acc[i][0] = acc[i][1] = acc[i][2] = acc[i][3] = 0.f;

  const int rg = tid / CG;
  const int cg = tid % CG;

  for (int kk = 0; kk < 128; kk += 32) {
    __syncthreads();
    for (int i = tid; i < 32 * CG; i += 256) {
      int kr = i / CG, f4 = i % CG;
      *(float4*)(&Ws[kr][f4 * 4]) = *(const float4*)(W + (size_t)(kk + kr) * DOUT + f4 * 4);
    }
    __syncthreads();
#pragma unroll
    for (int k = 0; k < 32; ++k) {
      float4 wv = *(const float4*)(&Ws[k][cg * 4]);
#pragma unroll
      for (int i = 0; i < RPT; ++i) {
        float a = Xs[rg * RPT + i][kk + k];
        acc[i][0] = fmaf(a, wv.x, acc[i][0]);
        acc[i][1] = fmaf(a, wv.y, acc[i][1]);
        acc[i][2] = fmaf(a, wv.z, acc[i][2]);
        acc[i][3] = fmaf(a, wv.w, acc[i][3]);
      }
    }
  }

#pragma unroll
  for (int i = 0; i < RPT; ++i) {
    int gr = r0 + rg * RPT + i;
    if (gr < n) {
      float4 o;
      o.x = acc[i][0]; o.y = acc[i][1]; o.z = acc[i][2]; o.w = acc[i][3];
      *(float4*)(XW + (size_t)gr * 128 + cg * 4) = o;
    }
  }
}

// pull-gather: h[i] = bias + dinv[i]^2 * xw[i] + sum_e nrm[e] * xw[row_e]
// one 64-lane wave per node, 4-deep load pipelining.
// FINAL: D=64, fuse L2-normalize, write d_out.
template<int D, bool FINAL>
__global__ __launch_bounds__(256) void gather_kernel(
    const int* __restrict__ rowptr, const int2* __restrict__ csr,
    const float* __restrict__ xw, const float* __restrict__ dinv,
    const float* __restrict__ bias, float* __restrict__ out, int n)
{
  int wid  = (blockIdx.x * blockDim.x + threadIdx.x) >> 6;
  int lane = threadIdx.x & 63;
  if (wid >= n) return;
  const int start = rowptr[wid];
  const int end   = rowptr[wid + 1];
  const float dv  = dinv[wid];
  const float dv2 = dv * dv;

  if constexpr (!FINAL) {
    const size_t c0 = (size_t)lane * 2;
    float2 self = *(const float2*)(xw + (size_t)wid * 128 + c0);
    float a0 = fmaf(self.x, dv2, bias[c0]);
    float a1 = fmaf(self.y, dv2, bias[c0 + 1]);
    int e = start;
    for (; e + 3 < end; e += 4) {
      int2 p0 = csr[e], p1 = csr[e + 1], p2 = csr[e + 2], p3 = csr[e + 3];
      float2 v0 = *(const float2*)(xw + (size_t)p0.x * 128 + c0);
      float2 v1 = *(const float2*)(xw + (size_t)p1.x * 128 + c0);
      float2 v2 = *(const float2*)(xw + (size_t)p2.x * 128 + c0);
      float2 v3 = *(const float2*)(xw + (size_t)p3.x * 128 + c0);
      float n0 = __int_as_float(p0.y), n1 = __int_as_float(p1.y);
      float n2 = __int_as_float(p2.y), n3 = __int_as_float(p3.y);
      a0 = fmaf(v0.x, n0, a0); a1 = fmaf(v0.y, n0, a1);
      a0 = fmaf(v1.x, n1, a0); a1 = fmaf(v1.y, n1, a1);
      a0 = fmaf(v2.x, n2, a0); a1 = fmaf(v2.y, n2, a1);
      a0 = fmaf(v3.x, n3, a0); a1 = fmaf(v3.y, n3, a1);
    }
    for (; e < end; ++e) {
      int2 p0 = csr[e];
      float2 v0 = *(const float2*)(xw + (size_t)p0.x * 128 + c0);
      float n0 = __int_as_float(p0.y);
      a0 = fmaf(v0.x, n0, a0); a1 = fmaf(v0.y, n0, a1);
    }
    *(float2*)(out + (size_t)wid * 128 + c0) = make_float2(a0, a1);
  } else {
    float self = xw[(size_t)wid * 128 + lane];
    float a = fmaf(self, dv2, bias[lane]);
    int e = start;
    for (; e + 3 < end; e += 4) {
      int2 p0 = csr[e], p1 = csr[e + 1], p2 = csr[e + 2], p3 = csr[e + 3];
      float v0 = xw[(size_t)p0.x * 128 + lane];
      float v1 = xw[(size_t)p1.x * 128 + lane];
      float v2 = xw[(size_t)p2.x * 128 + lane];
      float v3 = xw[(size_t)p3.x * 128 + lane];
      a = fmaf(v0, __int_as_float(p0.y), a);
      a = fmaf(v1, __int_as_float(p1.y), a);
      a = fmaf(v2, __int_as_float(p2.y), a);
      a = fmaf(v3, __int_as_float(p3.y), a);
    }
    for (; e < end; ++e) {
      int2 p0 = csr[e];
      float v0 = xw[(size_t)p0.x * 128 + lane];
      a = fmaf(v0, __int_as_float(p0.y), a);
    }
    float s = a * a;
#pragma unroll
    for (int off = 32; off >= 1; off >>= 1) s += __shfl_xor(s, off);
    float scale = 1.0f / fmaxf(sqrtf(s), 1e-12f);
    out[(size_t)wid * 64 + lane] = a * scale;
  }
}

extern "C" void kernel_launch(void* const* d_in, const int* in_sizes, int n_in,
                              void* d_out, int out_size, void* d_ws, size_t ws_size,
                              hipStream_t stream)
{
  const float* x   = (const float*)d_in[0];
  const int*   ei  = (const int*)d_in[1];
  const float* ew  = (const float*)d_in[2];
  const float* W1  = (const float*)d_in[3];
  const float* b1  = (const float*)d_in[4];
  const float* g1  = (const float*)d_in[5];
  const float* be1 = (const float*)d_in[6];
  const float* rm1 = (const float*)d_in[7];
  const float* rv1 = (const float*)d_in[8];
  const float* W2  = (const float*)d_in[9];
  const float* b2  = (const float*)d_in[10];
  const float* g2  = (const float*)d_in[11];
  const float* be2 = (const float*)d_in[12];
  const float* rm2 = (const float*)d_in[13];
  const float* rv2 = (const float*)d_in[14];
  const float* W3  = (const float*)d_in[15];
  const float* b3  = (const float*)d_in[16];

  const int N = in_sizes[0] / 128;
  const int E = in_sizes[2];
  const int* row = ei;       // edge_index[0]
  const int* col = ei + E;   // edge_index[1]

  char* ws = (char*)d_ws;
  size_t off = 0;
  auto alloc = [&](size_t bytes) -> void* {
    void* p = ws + off;
    off += (bytes + 255) & ~(size_t)255;
    return p;
  };
  float* deg    = (float*)alloc((size_t)N * 4);
  int*   cnt    = (int*)  alloc((size_t)N * 4);
  int*   cursor = (int*)  alloc((size_t)N * 4);
  float* dinv   = (float*)alloc((size_t)N * 4);
  int*   rowptr = (int*)  alloc((size_t)(N + 1) * 4);
  int*   bsum   = (int*)  alloc((size_t)1024 * 4);
  int2*  csr    = (int2*) alloc((size_t)E * 8);
  float* sc1    = (float*)alloc(512);
  float* sh1    = (float*)alloc(512);
  float* sc2    = (float*)alloc(512);
  float* sh2    = (float*)alloc(512);
  float* xw     = (float*)alloc((size_t)N * 128 * 4);
  float* h      = (float*)alloc((size_t)N * 128 * 4);

  hipMemsetAsync(deg, 0, (size_t)N * 4, stream);
  hipMemsetAsync(cnt, 0, (size_t)N * 4, stream);
  hipMemsetAsync(cursor, 0, (size_t)N * 4, stream);

  int gE = (E + TPB - 1) / TPB;
  int gN = (N + TPB - 1) / TPB;
  int nb = (N + 1023) / 1024;
  deg_kernel<<<gE, TPB, 0, stream>>>(col, ew, deg, cnt, E);
  dinv_kernel<<<gN, TPB, 0, stream>>>(deg, dinv, N);
  scan_partial<<<nb, 256, 0, stream>>>(cnt, bsum, N);
  scan_bsum<<<1, 1024, 0, stream>>>(bsum, nb, rowptr, N);
  scan_apply<<<nb, 256, 0, stream>>>(cnt, bsum, rowptr, N);
  fill_kernel<<<gE, TPB, 0, stream>>>(row, col, ew, dinv, rowptr, cursor, csr, E);
  bn_prep_kernel<<<1, 128, 0, stream>>>(g1, be1, rm1, rv1, g2, be2, rm2, rv2,
                                        sc1, sh1, sc2, sh2);

  const int gG  = (N + 31) / 32;       // gemm blocks
  const int gW  = (N + 3) / 4;         // gather blocks (4 waves/block)

  // layer 1
  gemm_kernel<128, false><<<gG, 256, 0, stream>>>(x, W1, nullptr, nullptr, xw, N);
  gather_kernel<128, false><<<gW, 256, 0, stream>>>(rowptr, csr, xw, dinv, b1, h, N);

  // layer 2
  gemm_kernel<128, true><<<gG, 256, 0, stream>>>(h, W2, sc1, sh1, xw, N);
  gather_kernel<128, false><<<gW, 256, 0, stream>>>(rowptr, csr, xw, dinv, b2, h, N);

  // layer 3 (DOUT=64, xw ld stays 128) + fused L2 normalize -> d_out
  gemm_kernel<64, true><<<gG, 256, 0, stream>>>(h, W3, sc2, sh2, xw, N);
  gather_kernel<64, true><<<gW, 256, 0, stream>>>(rowptr, csr, xw, dinv, b3, (float*)d_out, N);
}

// Round 4
// 533.528 us; speedup vs baseline: 13.0762x; 1.3491x over previous
//
#include <hip/hip_runtime.h>
#include <cstddef>

#define TPB 256

__device__ inline unsigned short f2bf(float f) {  // RNE float->bf16
  unsigned int u = __float_as_uint(f);
  return (unsigned short)((u + 0x7fffu + ((u >> 16) & 1u)) >> 16);
}
__device__ inline float bflo(unsigned int u) { return __uint_as_float(u << 16); }
__device__ inline float bfhi(unsigned int u) { return __uint_as_float(u & 0xffff0000u); }

// one packed 64-bit atomic per edge: [63:40]=count, [39:0]=sum(w) in 2^-30 fixed point
__global__ void deg_kernel(const int* __restrict__ col, const float* __restrict__ w,
                           unsigned long long* __restrict__ packed, int E) {
  int t = blockIdx.x * blockDim.x + threadIdx.x;
  if (t < E) {
    int c = col[t];
    unsigned long long v = (1ULL << 40) | (unsigned long long)(w[t] * 1073741824.0f);
    atomicAdd(&packed[c], v);
  }
}

// unpack: cnt + dinv
__global__ void unpack_kernel(const unsigned long long* __restrict__ packed,
                              int* __restrict__ cnt, float* __restrict__ dinv, int n) {
  int t = blockIdx.x * blockDim.x + threadIdx.x;
  if (t < n) {
    unsigned long long v = packed[t];
    cnt[t] = (int)(v >> 40);
    float deg = (float)(double)(v & ((1ULL << 40) - 1)) * 9.313225746154785e-10f;  // 2^-30
    dinv[t] = rsqrtf(deg + 1.0f);  // +1 = self-loop
  }
}

// ---- hierarchical scan: cnt[n] -> rowptr[n+1] (exclusive) ----
__global__ __launch_bounds__(256) void scan_partial(const int* __restrict__ cnt,
                                                    int* __restrict__ bsum, int n) {
  __shared__ int red[256];
  const int b = blockIdx.x, tid = threadIdx.x;
  const int base = b * 1024 + tid * 4;
  int s = 0;
  if (base + 3 < n) {
    int4 v = *(const int4*)(cnt + base);
    s = v.x + v.y + v.z + v.w;
  } else {
    for (int j = 0; j < 4; ++j) if (base + j < n) s += cnt[base + j];
  }
  red[tid] = s; __syncthreads();
  for (int off = 128; off >= 1; off >>= 1) {
    if (tid < off) red[tid] += red[tid + off];
    __syncthreads();
  }
  if (tid == 0) bsum[b] = red[0];
}

__global__ __launch_bounds__(1024) void scan_bsum(int* __restrict__ bsum, int nb,
                                                  int* __restrict__ rowptr, int n) {
  __shared__ int sh[1024];
  const int tid = threadIdx.x;
  int v = (tid < nb) ? bsum[tid] : 0;
  sh[tid] = v; __syncthreads();
  for (int off = 1; off < 1024; off <<= 1) {
    int t = (tid >= off) ? sh[tid - off] : 0;
    __syncthreads();
    sh[tid] += t;
    __syncthreads();
  }
  if (tid < nb) bsum[tid] = sh[tid] - v;   // exclusive
  if (tid == 1023) rowptr[n] = sh[1023];   // grand total
}

__global__ __launch_bounds__(256) void scan_apply(const int* __restrict__ cnt,
                                                  const int* __restrict__ bsum,
                                                  int* __restrict__ rowptr, int n) {
  __shared__ int red[256];
  const int b = blockIdx.x, tid = threadIdx.x;
  const int base = b * 1024 + tid * 4;
  int v0 = 0, v1 = 0, v2 = 0, v3 = 0;
  if (base + 3 < n) {
    int4 v = *(const int4*)(cnt + base);
    v0 = v.x; v1 = v.y; v2 = v.z; v3 = v.w;
  } else {
    if (base     < n) v0 = cnt[base];
    if (base + 1 < n) v1 = cnt[base + 1];
    if (base + 2 < n) v2 = cnt[base + 2];
    if (base + 3 < n) v3 = cnt[base + 3];
  }
  const int t = v0 + v1 + v2 + v3;
  red[tid] = t; __syncthreads();
  for (int off = 1; off < 256; off <<= 1) {
    int x = (tid >= off) ? red[tid - off] : 0;
    __syncthreads();
    red[tid] += x;
    __syncthreads();
  }
  int excl = red[tid] - t + bsum[b];
  if (base     < n) rowptr[base]     = excl;
  if (base + 1 < n) rowptr[base + 1] = excl + v0;
  if (base + 2 < n) rowptr[base + 2] = excl + v0 + v1;
  if (base + 3 < n) rowptr[base + 3] = excl + v0 + v1 + v2;
}

// csr[rowptr[col[e]] + pos] = (row[e], norm[e])
__global__ void fill_kernel(const int* __restrict__ row, const int* __restrict__ col,
                            const float* __restrict__ w, const float* __restrict__ dinv,
                            const int* __restrict__ rowptr, int* __restrict__ cursor,
                            int2* __restrict__ csr, int E) {
  int e = blockIdx.x * blockDim.x + threadIdx.x;
  if (e >= E) return;
  int r = row[e], c = col[e];
  float nm = dinv[r] * w[e] * dinv[c];
  int pos = atomicAdd(&cursor[c], 1);
  csr[rowptr[c] + pos] = make_int2(r, __float_as_int(nm));
}

__global__ void bn_prep_kernel(const float* g1, const float* be1, const float* rm1, const float* rv1,
                               const float* g2, const float* be2, const float* rm2, const float* rv2,
                               float* sc1, float* sh1, float* sc2, float* sh2) {
  int t = threadIdx.x;
  if (t < 128) {
    float s1 = g1[t] * rsqrtf(rv1[t] + 1e-5f);
    sc1[t] = s1; sh1[t] = be1[t] - rm1[t] * s1;
    float s2 = g2[t] * rsqrtf(rv2[t] + 1e-5f);
    sc2[t] = s2; sh2[t] = be2[t] - rm2[t] * s2;
  }
}

// X[N,128](f32) @ W[128,DOUT] -> XW packed bf16 (uint pairs, ld = DOUT/2 uints).
// BN+ReLU fused into X staging.
template<int DOUT, bool BN>
__global__ __launch_bounds__(256) void gemm_kernel(
    const float* __restrict__ X, const float* __restrict__ W,
    const float* __restrict__ bnsc, const float* __restrict__ bnsh,
    unsigned int* __restrict__ XWb, int n)
{
  constexpr int CG  = DOUT / 4;
  constexpr int RG  = 256 / CG;
  constexpr int RPT = 32 / RG;
  __shared__ float Xs[32][132];
  __shared__ float Ws[32][DOUT];
  const int tid = threadIdx.x;
  const int r0  = blockIdx.x * 32;

  for (int i = tid; i < 32 * 32; i += 256) {
    int rr = i >> 5, f4 = i & 31;
    int gr = r0 + rr;
    float4 v = make_float4(0.f, 0.f, 0.f, 0.f);
    if (gr < n) v = *(const float4*)(X + (size_t)gr * 128 + f4 * 4);
    if constexpr (BN) {
      int k = f4 * 4;
      v.x = fmaxf(fmaf(v.x, bnsc[k + 0], bnsh[k + 0]), 0.f);
      v.y = fmaxf(fmaf(v.y, bnsc[k + 1], bnsh[k + 1]), 0.f);
      v.z = fmaxf(fmaf(v.z, bnsc[k + 2], bnsh[k + 2]), 0.f);
      v.w = fmaxf(fmaf(v.w, bnsc[k + 3], bnsh[k + 3]), 0.f);
    }
    *(float4*)(&Xs[rr][f4 * 4]) = v;
  }

  float acc[RPT][4];
#pragma unroll
  for (int i = 0; i < RPT; ++i)
    acc[i][0] = acc[i][1] = acc[i][2] = acc[i][3] = 0.f;

  const int rg = tid / CG;
  const int cg = tid % CG;

  for (int kk = 0; kk < 128; kk += 32) {
    __syncthreads();
    for (int i = tid; i < 32 * CG; i += 256) {
      int kr = i / CG, f4 = i % CG;
      *(float4*)(&Ws[kr][f4 * 4]) = *(const float4*)(W + (size_t)(kk + kr) * DOUT + f4 * 4);
    }
    __syncthreads();
#pragma unroll
    for (int k = 0; k < 32; ++k) {
      float4 wv = *(const float4*)(&Ws[k][cg * 4]);
#pragma unroll
      for (int i = 0; i < RPT; ++i) {
        float a = Xs[rg * RPT + i][kk + k];
        acc[i][0] = fmaf(a, wv.x, acc[i][0]);
        acc[i][1] = fmaf(a, wv.y, acc[i][1]);
        acc[i][2] = fmaf(a, wv.z, acc[i][2]);
        acc[i][3] = fmaf(a, wv.w, acc[i][3]);
      }
    }
  }

#pragma unroll
  for (int i = 0; i < RPT; ++i) {
    int gr = r0 + rg * RPT + i;
    if (gr < n) {
      uint2 p;
      p.x = (unsigned int)f2bf(acc[i][0]) | ((unsigned int)f2bf(acc[i][1]) << 16);
      p.y = (unsigned int)f2bf(acc[i][2]) | ((unsigned int)f2bf(acc[i][3]) << 16);
      *(uint2*)(XWb + (size_t)gr * (DOUT / 2) + cg * 2) = p;
    }
  }
}

// pull-gather from bf16 xw: h[i] = bias + dinv[i]^2*xw[i] + sum_e nrm[e]*xw[row_e]
// one 64-lane wave per node. FINAL: D=64, fuse L2-normalize, write d_out (f32).
template<int D, bool FINAL>
__global__ __launch_bounds__(256) void gather_kernel(
    const int* __restrict__ rowptr, const int2* __restrict__ csr,
    const unsigned int* __restrict__ xwb, const float* __restrict__ dinv,
    const float* __restrict__ bias, float* __restrict__ out, int n)
{
  int wid  = (blockIdx.x * blockDim.x + threadIdx.x) >> 6;
  int lane = threadIdx.x & 63;
  if (wid >= n) return;
  const int start = rowptr[wid];
  const int end   = rowptr[wid + 1];
  const float dv  = dinv[wid];
  const float dv2 = dv * dv;

  if constexpr (!FINAL) {
    // D=128: lane handles cols (2*lane, 2*lane+1) = uint index `lane`, ld=64 uints
    unsigned int su = xwb[(size_t)wid * 64 + lane];
    float a0 = fmaf(bflo(su), dv2, bias[lane * 2]);
    float a1 = fmaf(bfhi(su), dv2, bias[lane * 2 + 1]);
    int e = start;
    for (; e + 3 < end; e += 4) {
      int2 p0 = csr[e], p1 = csr[e + 1], p2 = csr[e + 2], p3 = csr[e + 3];
      unsigned int u0 = xwb[(size_t)p0.x * 64 + lane];
      unsigned int u1 = xwb[(size_t)p1.x * 64 + lane];
      unsigned int u2 = xwb[(size_t)p2.x * 64 + lane];
      unsigned int u3 = xwb[(size_t)p3.x * 64 + lane];
      float n0 = __int_as_float(p0.y), n1 = __int_as_float(p1.y);
      float n2 = __int_as_float(p2.y), n3 = __int_as_float(p3.y);
      a0 = fmaf(bflo(u0), n0, a0); a1 = fmaf(bfhi(u0), n0, a1);
      a0 = fmaf(bflo(u1), n1, a0); a1 = fmaf(bfhi(u1), n1, a1);
      a0 = fmaf(bflo(u2), n2, a0); a1 = fmaf(bfhi(u2), n2, a1);
      a0 = fmaf(bflo(u3), n3, a0); a1 = fmaf(bfhi(u3), n3, a1);
    }
    for (; e < end; ++e) {
      int2 p0 = csr[e];
      unsigned int u0 = xwb[(size_t)p0.x * 64 + lane];
      float n0 = __int_as_float(p0.y);
      a0 = fmaf(bflo(u0), n0, a0); a1 = fmaf(bfhi(u0), n0, a1);
    }
    *(float2*)(out + (size_t)wid * 128 + lane * 2) = make_float2(a0, a1);
  } else {
    // D=64, ld=32 uints: lane handles col `lane`; pairs of lanes share a uint
    const int ui = lane >> 1;
    unsigned int su = xwb[(size_t)wid * 32 + ui];
    float self = (lane & 1) ? bfhi(su) : bflo(su);
    float a = fmaf(self, dv2, bias[lane]);
    int e = start;
    for (; e + 3 < end; e += 4) {
      int2 p0 = csr[e], p1 = csr[e + 1], p2 = csr[e + 2], p3 = csr[e + 3];
      unsigned int u0 = xwb[(size_t)p0.x * 32 + ui];
      unsigned int u1 = xwb[(size_t)p1.x * 32 + ui];
      unsigned int u2 = xwb[(size_t)p2.x * 32 + ui];
      unsigned int u3 = xwb[(size_t)p3.x * 32 + ui];
      float v0 = (lane & 1) ? bfhi(u0) : bflo(u0);
      float v1 = (lane & 1) ? bfhi(u1) : bflo(u1);
      float v2 = (lane & 1) ? bfhi(u2) : bflo(u2);
      float v3 = (lane & 1) ? bfhi(u3) : bflo(u3);
      a = fmaf(v0, __int_as_float(p0.y), a);
      a = fmaf(v1, __int_as_float(p1.y), a);
      a = fmaf(v2, __int_as_float(p2.y), a);
      a = fmaf(v3, __int_as_float(p3.y), a);
    }
    for (; e < end; ++e) {
      int2 p0 = csr[e];
      unsigned int u0 = xwb[(size_t)p0.x * 32 + ui];
      float v0 = (lane & 1) ? bfhi(u0) : bflo(u0);
      a = fmaf(v0, __int_as_float(p0.y), a);
    }
    float s = a * a;
#pragma unroll
    for (int off = 32; off >= 1; off >>= 1) s += __shfl_xor(s, off);
    float scale = 1.0f / fmaxf(sqrtf(s), 1e-12f);
    out[(size_t)wid * 64 + lane] = a * scale;
  }
}

extern "C" void kernel_launch(void* const* d_in, const int* in_sizes, int n_in,
                              void* d_out, int out_size, void* d_ws, size_t ws_size,
                              hipStream_t stream)
{
  const float* x   = (const float*)d_in[0];
  const int*   ei  = (const int*)d_in[1];
  const float* ew  = (const float*)d_in[2];
  const float* W1  = (const float*)d_in[3];
  const float* b1  = (const float*)d_in[4];
  const float* g1  = (const float*)d_in[5];
  const float* be1 = (const float*)d_in[6];
  const float* rm1 = (const float*)d_in[7];
  const float* rv1 = (const float*)d_in[8];
  const float* W2  = (const float*)d_in[9];
  const float* b2  = (const float*)d_in[10];
  const float* g2  = (const float*)d_in[11];
  const float* be2 = (const float*)d_in[12];
  const float* rm2 = (const float*)d_in[13];
  const float* rv2 = (const float*)d_in[14];
  const float* W3  = (const float*)d_in[15];
  const float* b3  = (const float*)d_in[16];

  const int N = in_sizes[0] / 128;
  const int E = in_sizes[2];
  const int* row = ei;       // edge_index[0]
  const int* col = ei + E;   // edge_index[1]

  char* ws = (char*)d_ws;
  size_t off = 0;
  auto alloc = [&](size_t bytes) -> void* {
    void* p = ws + off;
    off += (bytes + 255) & ~(size_t)255;
    return p;
  };
  unsigned long long* packed = (unsigned long long*)alloc((size_t)N * 8);
  int*   cnt    = (int*)  alloc((size_t)N * 4);
  int*   cursor = (int*)  alloc((size_t)N * 4);
  float* dinv   = (float*)alloc((size_t)N * 4);
  int*   rowptr = (int*)  alloc((size_t)(N + 1) * 4);
  int*   bsum   = (int*)  alloc((size_t)1024 * 4);
  int2*  csr    = (int2*) alloc((size_t)E * 8);
  float* sc1    = (float*)alloc(512);
  float* sh1    = (float*)alloc(512);
  float* sc2    = (float*)alloc(512);
  float* sh2    = (float*)alloc(512);
  unsigned int* xwb = (unsigned int*)alloc((size_t)N * 64 * 4);  // bf16-packed, ld<=64 uints
  float* h      = (float*)alloc((size_t)N * 128 * 4);

  hipMemsetAsync(packed, 0, (size_t)N * 8, stream);
  hipMemsetAsync(cursor, 0, (size_t)N * 4, stream);

  int gE = (E + TPB - 1) / TPB;
  int gN = (N + TPB - 1) / TPB;
  int nb = (N + 1023) / 1024;
  deg_kernel<<<gE, TPB, 0, stream>>>(col, ew, packed, E);
  unpack_kernel<<<gN, TPB, 0, stream>>>(packed, cnt, dinv, N);
  scan_partial<<<nb, 256, 0, stream>>>(cnt, bsum, N);
  scan_bsum<<<1, 1024, 0, stream>>>(bsum, nb, rowptr, N);
  scan_apply<<<nb, 256, 0, stream>>>(cnt, bsum, rowptr, N);
  fill_kernel<<<gE, TPB, 0, stream>>>(row, col, ew, dinv, rowptr, cursor, csr, E);
  bn_prep_kernel<<<1, 128, 0, stream>>>(g1, be1, rm1, rv1, g2, be2, rm2, rv2,
                                        sc1, sh1, sc2, sh2);

  const int gG = (N + 31) / 32;   // gemm blocks
  const int gW = (N + 3) / 4;     // gather blocks (4 waves/block)

  // layer 1
  gemm_kernel<128, false><<<gG, 256, 0, stream>>>(x, W1, nullptr, nullptr, xwb, N);
  gather_kernel<128, false><<<gW, 256, 0, stream>>>(rowptr, csr, xwb, dinv, b1, h, N);

  // layer 2
  gemm_kernel<128, true><<<gG, 256, 0, stream>>>(h, W2, sc1, sh1, xwb, N);
  gather_kernel<128, false><<<gW, 256, 0, stream>>>(rowptr, csr, xwb, dinv, b2, h, N);

  // layer 3 (DOUT=64, packed ld=32 uints) + fused L2 normalize -> d_out
  gemm_kernel<64, true><<<gG, 256, 0, stream>>>(h, W3, sc2, sh2, xwb, N);
  gather_kernel<64, true><<<gW, 256, 0, stream>>>(rowptr, csr, xwb, dinv, b3, (float*)d_out, N);
}

// Round 5
// 445.155 us; speedup vs baseline: 15.6721x; 1.1985x over previous
//
#include <hip/hip_runtime.h>
#include <cstddef>

#define TPB 256
#define AB_CHUNK 4096   // edges per phase-A block

__device__ inline unsigned short f2bf(float f) {  // RNE float->bf16
  unsigned int u = __float_as_uint(f);
  return (unsigned short)((u + 0x7fffu + ((u >> 16) & 1u)) >> 16);
}
__device__ inline float bflo(unsigned int u) { return __uint_as_float(u << 16); }
__device__ inline float bfhi(unsigned int u) { return __uint_as_float(u & 0xffff0000u); }

// ---- Phase A1: per-block coarse histogram (bucket = col>>8), LDS atomics only
__global__ __launch_bounds__(256) void histA(const int* __restrict__ col,
                                             int* __restrict__ cntmat,
                                             int E, int nbk, int nblkA) {
  __shared__ int hist[512];
  for (int i = threadIdx.x; i < nbk; i += 256) hist[i] = 0;
  __syncthreads();
  const int base = blockIdx.x * AB_CHUNK;
  const int lim  = min(base + AB_CHUNK, E);
  for (int i = base + threadIdx.x; i < lim; i += 256)
    atomicAdd(&hist[col[i] >> 8], 1);
  __syncthreads();
  for (int k = threadIdx.x; k < nbk; k += 256)
    cntmat[k * nblkA + blockIdx.x] = hist[k];   // bucket-major
}

// ---- hierarchical exclusive scan (arbitrary n; out[n] = total) ----
__global__ __launch_bounds__(256) void scan_partial(const int* __restrict__ cnt,
                                                    int* __restrict__ bsum, int n) {
  __shared__ int red[256];
  const int b = blockIdx.x, tid = threadIdx.x;
  const int base = b * 1024 + tid * 4;
  int s = 0;
  if (base + 3 < n) {
    int4 v = *(const int4*)(cnt + base);
    s = v.x + v.y + v.z + v.w;
  } else {
    for (int j = 0; j < 4; ++j) if (base + j < n) s += cnt[base + j];
  }
  red[tid] = s; __syncthreads();
  for (int off = 128; off >= 1; off >>= 1) {
    if (tid < off) red[tid] += red[tid + off];
    __syncthreads();
  }
  if (tid == 0) bsum[b] = red[0];
}

__global__ __launch_bounds__(1024) void scan_bsum(int* __restrict__ bsum, int nb,
                                                  int* __restrict__ out, int n) {
  __shared__ int sh[1024];
  const int tid = threadIdx.x;
  int v = (tid < nb) ? bsum[tid] : 0;
  sh[tid] = v; __syncthreads();
  for (int off = 1; off < 1024; off <<= 1) {
    int t = (tid >= off) ? sh[tid - off] : 0;
    __syncthreads();
    sh[tid] += t;
    __syncthreads();
  }
  if (tid < nb) bsum[tid] = sh[tid] - v;   // exclusive
  if (tid == 1023) out[n] = sh[1023];      // grand total
}

__global__ __launch_bounds__(256) void scan_apply(const int* __restrict__ cnt,
                                                  const int* __restrict__ bsum,
                                                  int* __restrict__ out, int n) {
  __shared__ int red[256];
  const int b = blockIdx.x, tid = threadIdx.x;
  const int base = b * 1024 + tid * 4;
  int v0 = 0, v1 = 0, v2 = 0, v3 = 0;
  if (base + 3 < n) {
    int4 v = *(const int4*)(cnt + base);
    v0 = v.x; v1 = v.y; v2 = v.z; v3 = v.w;
  } else {
    if (base     < n) v0 = cnt[base];
    if (base + 1 < n) v1 = cnt[base + 1];
    if (base + 2 < n) v2 = cnt[base + 2];
    if (base + 3 < n) v3 = cnt[base + 3];
  }
  const int t = v0 + v1 + v2 + v3;
  red[tid] = t; __syncthreads();
  for (int off = 1; off < 256; off <<= 1) {
    int x = (tid >= off) ? red[tid - off] : 0;
    __syncthreads();
    red[tid] += x;
    __syncthreads();
  }
  int excl = red[tid] - t + bsum[b];
  if (base     < n) out[base]     = excl;
  if (base + 1 < n) out[base + 1] = excl + v0;
  if (base + 2 < n) out[base + 2] = excl + v0 + v1;
  if (base + 3 < n) out[base + 3] = excl + v0 + v1 + v2;
}

// ---- Phase A3: scatter edges into bucket-contiguous order
// payload: {row | (col&255)<<17, w_bits}  (row < 2^17, col_local < 256)
__global__ __launch_bounds__(256) void scatA(const int* __restrict__ row,
                                             const int* __restrict__ col,
                                             const float* __restrict__ w,
                                             const int* __restrict__ scnt,
                                             int2* __restrict__ bucketed,
                                             int E, int nbk, int nblkA) {
  __shared__ int cur[512];
  for (int k = threadIdx.x; k < nbk; k += 256)
    cur[k] = scnt[k * nblkA + blockIdx.x];
  __syncthreads();
  const int base = blockIdx.x * AB_CHUNK;
  const int lim  = min(base + AB_CHUNK, E);
  for (int i = base + threadIdx.x; i < lim; i += 256) {
    int c = col[i];
    int pos = atomicAdd(&cur[c >> 8], 1);
    bucketed[pos] = make_int2(row[i] | ((c & 255) << 17), __float_as_int(w[i]));
  }
}

// ---- Phase B: per-bucket (256 nodes) local sort -> CSR + rowptr + dinv
__global__ __launch_bounds__(256) void bucketB(const int2* __restrict__ bucketed,
                                               const int* __restrict__ scnt,
                                               int2* __restrict__ csr,
                                               int* __restrict__ rowptr,
                                               float* __restrict__ dinv,
                                               int E, int N, int nbk, int nblkA) {
  __shared__ int   hist[256];   // then reused as cursor
  __shared__ float degf[256];
  __shared__ int   excl[256];
  const int b = blockIdx.x, tid = threadIdx.x;
  const int start = scnt[b * nblkA];
  const int end   = (b == nbk - 1) ? E : scnt[(b + 1) * nblkA];
  hist[tid] = 0; degf[tid] = 0.f;
  __syncthreads();
  for (int i = start + tid; i < end; i += 256) {
    int2 p = bucketed[i];
    int cl = (p.x >> 17) & 255;
    atomicAdd(&hist[cl], 1);
    atomicAdd(&degf[cl], __int_as_float(p.y));
  }
  __syncthreads();
  const int v = hist[tid];
  excl[tid] = v;
  __syncthreads();
  for (int off = 1; off < 256; off <<= 1) {
    int t = (tid >= off) ? excl[tid - off] : 0;
    __syncthreads();
    excl[tid] += t;
    __syncthreads();
  }
  const int ex = excl[tid] - v;  // exclusive prefix within bucket
  const int node = b * 256 + tid;
  if (node < N) {
    rowptr[node] = start + ex;
    dinv[node]   = rsqrtf(degf[tid] + 1.0f);   // +1 = self-loop
  }
  if (b == nbk - 1 && tid == 0) rowptr[N] = E;
  __syncthreads();
  hist[tid] = ex;       // reuse as running cursor
  __syncthreads();
  for (int i = start + tid; i < end; i += 256) {
    int2 p = bucketed[i];
    int cl = (p.x >> 17) & 255;
    int pos = start + atomicAdd(&hist[cl], 1);
    csr[pos] = make_int2(p.x & 0x1FFFF, p.y);   // {row, w}
  }
}

__global__ void bn_prep_kernel(const float* g1, const float* be1, const float* rm1, const float* rv1,
                               const float* g2, const float* be2, const float* rm2, const float* rv2,
                               float* sc1, float* sh1, float* sc2, float* sh2) {
  int t = threadIdx.x;
  if (t < 128) {
    float s1 = g1[t] * rsqrtf(rv1[t] + 1e-5f);
    sc1[t] = s1; sh1[t] = be1[t] - rm1[t] * s1;
    float s2 = g2[t] * rsqrtf(rv2[t] + 1e-5f);
    sc2[t] = s2; sh2[t] = be2[t] - rm2[t] * s2;
  }
}

// X[N,128](f32) @ W[128,DOUT] -> y = dinv[r]*(XW) packed bf16 (ld = DOUT/2 uints).
// BN+ReLU fused into X staging.
template<int DOUT, bool BN>
__global__ __launch_bounds__(256) void gemm_kernel(
    const float* __restrict__ X, const float* __restrict__ W,
    const float* __restrict__ bnsc, const float* __restrict__ bnsh,
    const float* __restrict__ dinv,
    unsigned int* __restrict__ XWb, int n)
{
  constexpr int CG  = DOUT / 4;
  constexpr int RG  = 256 / CG;
  constexpr int RPT = 32 / RG;
  __shared__ float Xs[32][132];
  __shared__ float Ws[32][DOUT];
  const int tid = threadIdx.x;
  const int r0  = blockIdx.x * 32;

  for (int i = tid; i < 32 * 32; i += 256) {
    int rr = i >> 5, f4 = i & 31;
    int gr = r0 + rr;
    float4 v = make_float4(0.f, 0.f, 0.f, 0.f);
    if (gr < n) v = *(const float4*)(X + (size_t)gr * 128 + f4 * 4);
    if constexpr (BN) {
      int k = f4 * 4;
      v.x = fmaxf(fmaf(v.x, bnsc[k + 0], bnsh[k + 0]), 0.f);
      v.y = fmaxf(fmaf(v.y, bnsc[k + 1], bnsh[k + 1]), 0.f);
      v.z = fmaxf(fmaf(v.z, bnsc[k + 2], bnsh[k + 2]), 0.f);
      v.w = fmaxf(fmaf(v.w, bnsc[k + 3], bnsh[k + 3]), 0.f);
    }
    *(float4*)(&Xs[rr][f4 * 4]) = v;
  }

  float acc[RPT][4];
#pragma unroll
  for (int i = 0; i < RPT; ++i)
    acc[i][0] = acc[i][1] = acc[i][2] = acc[i][3] = 0.f;

  const int rg = tid / CG;
  const int cg = tid % CG;

  for (int kk = 0; kk < 128; kk += 32) {
    __syncthreads();
    for (int i = tid; i < 32 * CG; i += 256) {
      int kr = i / CG, f4 = i % CG;
      *(float4*)(&Ws[kr][f4 * 4]) = *(const float4*)(W + (size_t)(kk + kr) * DOUT + f4 * 4);
    }
    __syncthreads();
#pragma unroll
    for (int k = 0; k < 32; ++k) {
      float4 wv = *(const float4*)(&Ws[k][cg * 4]);
#pragma unroll
      for (int i = 0; i < RPT; ++i) {
        float a = Xs[rg * RPT + i][kk + k];
        acc[i][0] = fmaf(a, wv.x, acc[i][0]);
        acc[i][1] = fmaf(a, wv.y, acc[i][1]);
        acc[i][2] = fmaf(a, wv.z, acc[i][2]);
        acc[i][3] = fmaf(a, wv.w, acc[i][3]);
      }
    }
  }

#pragma unroll
  for (int i = 0; i < RPT; ++i) {
    int gr = r0 + rg * RPT + i;
    if (gr < n) {
      float dv = dinv[gr];
      uint2 p;
      p.x = (unsigned int)f2bf(acc[i][0] * dv) | ((unsigned int)f2bf(acc[i][1] * dv) << 16);
      p.y = (unsigned int)f2bf(acc[i][2] * dv) | ((unsigned int)f2bf(acc[i][3] * dv) << 16);
      *(uint2*)(XWb + (size_t)gr * (DOUT / 2) + cg * 2) = p;
    }
  }
}

// pull-gather from bf16 y: h[i] = bias + dinv[i]*( y_i + sum_e w_e * y_{row_e} )
// one 64-lane wave per node. FINAL: D=64, fuse L2-normalize, write d_out (f32).
template<int D, bool FINAL>
__global__ __launch_bounds__(256) void gather_kernel(
    const int* __restrict__ rowptr, const int2* __restrict__ csr,
    const unsigned int* __restrict__ xwb, const float* __restrict__ dinv,
    const float* __restrict__ bias, float* __restrict__ out, int n)
{
  int wid  = (blockIdx.x * blockDim.x + threadIdx.x) >> 6;
  int lane = threadIdx.x & 63;
  if (wid >= n) return;
  const int start = rowptr[wid];
  const int end   = rowptr[wid + 1];
  const float dv  = dinv[wid];

  if constexpr (!FINAL) {
    // D=128: lane handles cols (2*lane, 2*lane+1) = uint index `lane`, ld=64 uints
    unsigned int su = xwb[(size_t)wid * 64 + lane];
    float a0 = bflo(su), a1 = bfhi(su);
    int e = start;
    for (; e + 3 < end; e += 4) {
      int2 p0 = csr[e], p1 = csr[e + 1], p2 = csr[e + 2], p3 = csr[e + 3];
      unsigned int u0 = xwb[(size_t)p0.x * 64 + lane];
      unsigned int u1 = xwb[(size_t)p1.x * 64 + lane];
      unsigned int u2 = xwb[(size_t)p2.x * 64 + lane];
      unsigned int u3 = xwb[(size_t)p3.x * 64 + lane];
      float n0 = __int_as_float(p0.y), n1 = __int_as_float(p1.y);
      float n2 = __int_as_float(p2.y), n3 = __int_as_float(p3.y);
      a0 = fmaf(bflo(u0), n0, a0); a1 = fmaf(bfhi(u0), n0, a1);
      a0 = fmaf(bflo(u1), n1, a0); a1 = fmaf(bfhi(u1), n1, a1);
      a0 = fmaf(bflo(u2), n2, a0); a1 = fmaf(bfhi(u2), n2, a1);
      a0 = fmaf(bflo(u3), n3, a0); a1 = fmaf(bfhi(u3), n3, a1);
    }
    for (; e < end; ++e) {
      int2 p0 = csr[e];
      unsigned int u0 = xwb[(size_t)p0.x * 64 + lane];
      float n0 = __int_as_float(p0.y);
      a0 = fmaf(bflo(u0), n0, a0); a1 = fmaf(bfhi(u0), n0, a1);
    }
    a0 = fmaf(dv, a0, bias[lane * 2]);
    a1 = fmaf(dv, a1, bias[lane * 2 + 1]);
    *(float2*)(out + (size_t)wid * 128 + lane * 2) = make_float2(a0, a1);
  } else {
    // D=64, ld=32 uints: lane handles col `lane`; pairs of lanes share a uint
    const int ui = lane >> 1;
    unsigned int su = xwb[(size_t)wid * 32 + ui];
    float a = (lane & 1) ? bfhi(su) : bflo(su);
    int e = start;
    for (; e + 3 < end; e += 4) {
      int2 p0 = csr[e], p1 = csr[e + 1], p2 = csr[e + 2], p3 = csr[e + 3];
      unsigned int u0 = xwb[(size_t)p0.x * 32 + ui];
      unsigned int u1 = xwb[(size_t)p1.x * 32 + ui];
      unsigned int u2 = xwb[(size_t)p2.x * 32 + ui];
      unsigned int u3 = xwb[(size_t)p3.x * 32 + ui];
      float v0 = (lane & 1) ? bfhi(u0) : bflo(u0);
      float v1 = (lane & 1) ? bfhi(u1) : bflo(u1);
      float v2 = (lane & 1) ? bfhi(u2) : bflo(u2);
      float v3 = (lane & 1) ? bfhi(u3) : bflo(u3);
      a = fmaf(v0, __int_as_float(p0.y), a);
      a = fmaf(v1, __int_as_float(p1.y), a);
      a = fmaf(v2, __int_as_float(p2.y), a);
      a = fmaf(v3, __int_as_float(p3.y), a);
    }
    for (; e < end; ++e) {
      int2 p0 = csr[e];
      unsigned int u0 = xwb[(size_t)p0.x * 32 + ui];
      float v0 = (lane & 1) ? bfhi(u0) : bflo(u0);
      a = fmaf(v0, __int_as_float(p0.y), a);
    }
    a = fmaf(dv, a, bias[lane]);
    float s = a * a;
#pragma unroll
    for (int off = 32; off >= 1; off >>= 1) s += __shfl_xor(s, off);
    float scale = 1.0f / fmaxf(sqrtf(s), 1e-12f);
    out[(size_t)wid * 64 + lane] = a * scale;
  }
}

extern "C" void kernel_launch(void* const* d_in, const int* in_sizes, int n_in,
                              void* d_out, int out_size, void* d_ws, size_t ws_size,
                              hipStream_t stream)
{
  const float* x   = (const float*)d_in[0];
  const int*   ei  = (const int*)d_in[1];
  const float* ew  = (const float*)d_in[2];
  const float* W1  = (const float*)d_in[3];
  const float* b1  = (const float*)d_in[4];
  const float* g1  = (const float*)d_in[5];
  const float* be1 = (const float*)d_in[6];
  const float* rm1 = (const float*)d_in[7];
  const float* rv1 = (const float*)d_in[8];
  const float* W2  = (const float*)d_in[9];
  const float* b2  = (const float*)d_in[10];
  const float* g2  = (const float*)d_in[11];
  const float* be2 = (const float*)d_in[12];
  const float* rm2 = (const float*)d_in[13];
  const float* rv2 = (const float*)d_in[14];
  const float* W3  = (const float*)d_in[15];
  const float* b3  = (const float*)d_in[16];

  const int N = in_sizes[0] / 128;
  const int E = in_sizes[2];
  const int* row = ei;       // edge_index[0]
  const int* col = ei + E;   // edge_index[1]

  const int nbk   = (N + 255) >> 8;                 // coarse buckets (col>>8)
  const int nblkA = (E + AB_CHUNK - 1) / AB_CHUNK;  // phase-A blocks
  const int L     = nbk * nblkA;                    // count-matrix length
  const int nb2   = (L + 1023) / 1024;              // scan partial blocks (<=1024)

  char* ws = (char*)d_ws;
  size_t off = 0;
  auto alloc = [&](size_t bytes) -> void* {
    void* p = ws + off;
    off += (bytes + 255) & ~(size_t)255;
    return p;
  };
  int*   cntmat = (int*)  alloc((size_t)L * 4);
  int*   scnt   = (int*)  alloc((size_t)(L + 1) * 4);
  int*   bsum   = (int*)  alloc((size_t)1024 * 4);
  int2*  bucketed = (int2*)alloc((size_t)E * 8);
  int2*  csr    = (int2*) alloc((size_t)E * 8);
  int*   rowptr = (int*)  alloc((size_t)(N + 1) * 4);
  float* dinv   = (float*)alloc((size_t)N * 4);
  float* sc1    = (float*)alloc(512);
  float* sh1    = (float*)alloc(512);
  float* sc2    = (float*)alloc(512);
  float* sh2    = (float*)alloc(512);
  unsigned int* xwb = (unsigned int*)alloc((size_t)N * 64 * 4);  // bf16-packed y
  float* h      = (float*)alloc((size_t)N * 128 * 4);

  // ---- CSR build (deterministic two-level bucket sort; no global atomics) ----
  histA<<<nblkA, 256, 0, stream>>>(col, cntmat, E, nbk, nblkA);
  scan_partial<<<nb2, 256, 0, stream>>>(cntmat, bsum, L);
  scan_bsum<<<1, 1024, 0, stream>>>(bsum, nb2, scnt, L);
  scan_apply<<<nb2, 256, 0, stream>>>(cntmat, bsum, scnt, L);
  scatA<<<nblkA, 256, 0, stream>>>(row, col, ew, scnt, bucketed, E, nbk, nblkA);
  bucketB<<<nbk, 256, 0, stream>>>(bucketed, scnt, csr, rowptr, dinv, E, N, nbk, nblkA);
  bn_prep_kernel<<<1, 128, 0, stream>>>(g1, be1, rm1, rv1, g2, be2, rm2, rv2,
                                        sc1, sh1, sc2, sh2);

  const int gG = (N + 31) / 32;   // gemm blocks
  const int gW = (N + 3) / 4;     // gather blocks (4 waves/block)

  // layer 1
  gemm_kernel<128, false><<<gG, 256, 0, stream>>>(x, W1, nullptr, nullptr, dinv, xwb, N);
  gather_kernel<128, false><<<gW, 256, 0, stream>>>(rowptr, csr, xwb, dinv, b1, h, N);

  // layer 2
  gemm_kernel<128, true><<<gG, 256, 0, stream>>>(h, W2, sc1, sh1, dinv, xwb, N);
  gather_kernel<128, false><<<gW, 256, 0, stream>>>(rowptr, csr, xwb, dinv, b2, h, N);

  // layer 3 (DOUT=64, packed ld=32 uints) + fused L2 normalize -> d_out
  gemm_kernel<64, true><<<gG, 256, 0, stream>>>(h, W3, sc2, sh2, dinv, xwb, N);
  gather_kernel<64, true><<<gW, 256, 0, stream>>>(rowptr, csr, xwb, dinv, b3, (float*)d_out, N);
}

// Round 6
// 357.545 us; speedup vs baseline: 19.5123x; 1.2450x over previous
//
#include <hip/hip_runtime.h>
#include <cstddef>

#define TPB 256
#define AB_CHUNK 4096   // edges per phase-A block

typedef __attribute__((ext_vector_type(8))) short short8;   // 8 bf16 (4 VGPRs)
typedef __attribute__((ext_vector_type(4))) float f32x4;    // MFMA C/D frag

__device__ inline unsigned short f2bf(float f) {  // RNE float->bf16
  unsigned int u = __float_as_uint(f);
  return (unsigned short)((u + 0x7fffu + ((u >> 16) & 1u)) >> 16);
}
__device__ inline float bflo(unsigned int u) { return __uint_as_float(u << 16); }
__device__ inline float bfhi(unsigned int u) { return __uint_as_float(u & 0xffff0000u); }

// ---- Phase A1: per-block coarse histogram (bucket = col>>8), LDS atomics only
__global__ __launch_bounds__(256) void histA(const int* __restrict__ col,
                                             int* __restrict__ cntmat,
                                             int E, int nbk, int nblkA) {
  __shared__ int hist[512];
  for (int i = threadIdx.x; i < nbk; i += 256) hist[i] = 0;
  __syncthreads();
  const int base = blockIdx.x * AB_CHUNK;
  const int lim  = min(base + AB_CHUNK, E);
  for (int i = base + threadIdx.x; i < lim; i += 256)
    atomicAdd(&hist[col[i] >> 8], 1);
  __syncthreads();
  for (int k = threadIdx.x; k < nbk; k += 256)
    cntmat[k * nblkA + blockIdx.x] = hist[k];   // bucket-major
}

// ---- hierarchical exclusive scan (arbitrary n; out[n] = total) ----
__global__ __launch_bounds__(256) void scan_partial(const int* __restrict__ cnt,
                                                    int* __restrict__ bsum, int n) {
  __shared__ int red[256];
  const int b = blockIdx.x, tid = threadIdx.x;
  const int base = b * 1024 + tid * 4;
  int s = 0;
  if (base + 3 < n) {
    int4 v = *(const int4*)(cnt + base);
    s = v.x + v.y + v.z + v.w;
  } else {
    for (int j = 0; j < 4; ++j) if (base + j < n) s += cnt[base + j];
  }
  red[tid] = s; __syncthreads();
  for (int off = 128; off >= 1; off >>= 1) {
    if (tid < off) red[tid] += red[tid + off];
    __syncthreads();
  }
  if (tid == 0) bsum[b] = red[0];
}

__global__ __launch_bounds__(1024) void scan_bsum(int* __restrict__ bsum, int nb,
                                                  int* __restrict__ out, int n) {
  __shared__ int sh[1024];
  const int tid = threadIdx.x;
  int v = (tid < nb) ? bsum[tid] : 0;
  sh[tid] = v; __syncthreads();
  for (int off = 1; off < 1024; off <<= 1) {
    int t = (tid >= off) ? sh[tid - off] : 0;
    __syncthreads();
    sh[tid] += t;
    __syncthreads();
  }
  if (tid < nb) bsum[tid] = sh[tid] - v;   // exclusive
  if (tid == 1023) out[n] = sh[1023];      // grand total
}

__global__ __launch_bounds__(256) void scan_apply(const int* __restrict__ cnt,
                                                  const int* __restrict__ bsum,
                                                  int* __restrict__ out, int n) {
  __shared__ int red[256];
  const int b = blockIdx.x, tid = threadIdx.x;
  const int base = b * 1024 + tid * 4;
  int v0 = 0, v1 = 0, v2 = 0, v3 = 0;
  if (base + 3 < n) {
    int4 v = *(const int4*)(cnt + base);
    v0 = v.x; v1 = v.y; v2 = v.z; v3 = v.w;
  } else {
    if (base     < n) v0 = cnt[base];
    if (base + 1 < n) v1 = cnt[base + 1];
    if (base + 2 < n) v2 = cnt[base + 2];
    if (base + 3 < n) v3 = cnt[base + 3];
  }
  const int t = v0 + v1 + v2 + v3;
  red[tid] = t; __syncthreads();
  for (int off = 1; off < 256; off <<= 1) {
    int x = (tid >= off) ? red[tid - off] : 0;
    __syncthreads();
    red[tid] += x;
    __syncthreads();
  }
  int excl = red[tid] - t + bsum[b];
  if (base     < n) out[base]     = excl;
  if (base + 1 < n) out[base + 1] = excl + v0;
  if (base + 2 < n) out[base + 2] = excl + v0 + v1;
  if (base + 3 < n) out[base + 3] = excl + v0 + v1 + v2;
}

// ---- Phase A3: scatter edges into bucket-contiguous order
// payload: {row | (col&255)<<17, w_bits}  (row < 2^17, col_local < 256)
__global__ __launch_bounds__(256) void scatA(const int* __restrict__ row,
                                             const int* __restrict__ col,
                                             const float* __restrict__ w,
                                             const int* __restrict__ scnt,
                                             int2* __restrict__ bucketed,
                                             int E, int nbk, int nblkA) {
  __shared__ int cur[512];
  for (int k = threadIdx.x; k < nbk; k += 256)
    cur[k] = scnt[k * nblkA + blockIdx.x];
  __syncthreads();
  const int base = blockIdx.x * AB_CHUNK;
  const int lim  = min(base + AB_CHUNK, E);
  for (int i = base + threadIdx.x; i < lim; i += 256) {
    int c = col[i];
    int pos = atomicAdd(&cur[c >> 8], 1);
    bucketed[pos] = make_int2(row[i] | ((c & 255) << 17), __float_as_int(w[i]));
  }
}

// ---- Phase B: per-bucket (256 nodes) local sort -> CSR + rowptr + dinv
__global__ __launch_bounds__(256) void bucketB(const int2* __restrict__ bucketed,
                                               const int* __restrict__ scnt,
                                               int2* __restrict__ csr,
                                               int* __restrict__ rowptr,
                                               float* __restrict__ dinv,
                                               int E, int N, int nbk, int nblkA) {
  __shared__ int   hist[256];   // then reused as cursor
  __shared__ float degf[256];
  __shared__ int   excl[256];
  const int b = blockIdx.x, tid = threadIdx.x;
  const int start = scnt[b * nblkA];
  const int end   = (b == nbk - 1) ? E : scnt[(b + 1) * nblkA];
  hist[tid] = 0; degf[tid] = 0.f;
  __syncthreads();
  for (int i = start + tid; i < end; i += 256) {
    int2 p = bucketed[i];
    int cl = (p.x >> 17) & 255;
    atomicAdd(&hist[cl], 1);
    atomicAdd(&degf[cl], __int_as_float(p.y));
  }
  __syncthreads();
  const int v = hist[tid];
  excl[tid] = v;
  __syncthreads();
  for (int off = 1; off < 256; off <<= 1) {
    int t = (tid >= off) ? excl[tid - off] : 0;
    __syncthreads();
    excl[tid] += t;
    __syncthreads();
  }
  const int ex = excl[tid] - v;  // exclusive prefix within bucket
  const int node = b * 256 + tid;
  if (node < N) {
    rowptr[node] = start + ex;
    dinv[node]   = rsqrtf(degf[tid] + 1.0f);   // +1 = self-loop
  }
  if (b == nbk - 1 && tid == 0) rowptr[N] = E;
  __syncthreads();
  hist[tid] = ex;       // reuse as running cursor
  __syncthreads();
  for (int i = start + tid; i < end; i += 256) {
    int2 p = bucketed[i];
    int cl = (p.x >> 17) & 255;
    int pos = start + atomicAdd(&hist[cl], 1);
    csr[pos] = make_int2(p.x & 0x1FFFF, p.y);   // {row, w}
  }
}

__global__ void bn_prep_kernel(const float* g1, const float* be1, const float* rm1, const float* rv1,
                               const float* g2, const float* be2, const float* rm2, const float* rv2,
                               float* sc1, float* sh1, float* sc2, float* sh2) {
  int t = threadIdx.x;
  if (t < 128) {
    float s1 = g1[t] * rsqrtf(rv1[t] + 1e-5f);
    sc1[t] = s1; sh1[t] = be1[t] - rm1[t] * s1;
    float s2 = g2[t] * rsqrtf(rv2[t] + 1e-5f);
    sc2[t] = s2; sh2[t] = be2[t] - rm2[t] * s2;
  }
}

// W[128,DOUT] f32 -> Wt[DOUT,128] bf16 (transposed, for B-frag ds_read_b128)
__global__ void wt_kernel(const float* __restrict__ W, unsigned short* __restrict__ Wt, int DOUT) {
  int t = blockIdx.x * blockDim.x + threadIdx.x;   // t < DOUT*128
  int nidx = t >> 7, k = t & 127;
  Wt[t] = f2bf(W[(size_t)k * DOUT + nidx]);
}

// MFMA GEMM: Xbf[64-row tile] @ W -> y = dinv[r]*(X@W) packed bf16 (ld = DOUT/2 uints)
// A-frag: row=lane&15, k=(lane>>4)*8+j ; B-frag: col=lane&15, same k
// C/D: col=lane&15, row=(lane>>4)*4+reg   [verified m89/m91 mapping]
template<int DOUT, bool BF16IN>
__global__ __launch_bounds__(256) void gemm_mfma(
    const void* Xin,                         // f32[N,128] or packed-bf16 uint[N,64]
    const unsigned short* __restrict__ Wt,   // bf16 [DOUT][128]
    const float* __restrict__ dinv,
    unsigned int* __restrict__ XWb, int n)
{
  constexpr int CT = DOUT / 16;
  __shared__ unsigned short Xs[64][136];     // +8 pad: 2-way banks (free)
  __shared__ unsigned short Ws[DOUT][136];
  const int tid = threadIdx.x;
  const int r0  = blockIdx.x * 64;

  if constexpr (BF16IN) {
    const unsigned int* hb = (const unsigned int*)Xin;
    for (int i = tid; i < 64 * 16; i += 256) {           // uint4 = 8 bf16
      int rr = i >> 4, q = i & 15;
      uint4 v = make_uint4(0, 0, 0, 0);
      if (r0 + rr < n) v = *(const uint4*)(hb + (size_t)(r0 + rr) * 64 + q * 4);
      *(uint4*)(&Xs[rr][q * 8]) = v;
    }
  } else {
    const float* X = (const float*)Xin;
    for (int i = tid; i < 64 * 32; i += 256) {           // float4 -> 4 bf16
      int rr = i >> 5, q = i & 31;
      float4 v = make_float4(0.f, 0.f, 0.f, 0.f);
      if (r0 + rr < n) v = *(const float4*)(X + (size_t)(r0 + rr) * 128 + q * 4);
      uint2 p;
      p.x = (unsigned)f2bf(v.x) | ((unsigned)f2bf(v.y) << 16);
      p.y = (unsigned)f2bf(v.z) | ((unsigned)f2bf(v.w) << 16);
      *(uint2*)(&Xs[rr][q * 4]) = p;
    }
  }
  for (int i = tid; i < DOUT * 16; i += 256) {
    int nr = i >> 4, q = i & 15;
    *(uint4*)(&Ws[nr][q * 8]) = *(const uint4*)(Wt + (size_t)nr * 128 + q * 8);
  }
  __syncthreads();

  const int wid  = tid >> 6, lane = tid & 63;
  const int arow = wid * 16 + (lane & 15);
  const int koff = (lane >> 4) << 3;

  short8 af[4];
#pragma unroll
  for (int s = 0; s < 4; ++s)
    af[s] = *(const short8*)(&Xs[arow][s * 32 + koff]);

  f32x4 acc[CT];
#pragma unroll
  for (int ct = 0; ct < CT; ++ct) acc[ct] = (f32x4){0.f, 0.f, 0.f, 0.f};

#pragma unroll
  for (int ct = 0; ct < CT; ++ct) {
    const int brow = ct * 16 + (lane & 15);
#pragma unroll
    for (int s = 0; s < 4; ++s) {
      short8 bf = *(const short8*)(&Ws[brow][s * 32 + koff]);
      acc[ct] = __builtin_amdgcn_mfma_f32_16x16x32_bf16(af[s], bf, acc[ct], 0, 0, 0);
    }
  }

  const int rbase = r0 + wid * 16 + ((lane >> 4) << 2);
  float dvv[4];
#pragma unroll
  for (int i = 0; i < 4; ++i) dvv[i] = (rbase + i < n) ? dinv[rbase + i] : 0.f;

#pragma unroll
  for (int ct = 0; ct < CT; ++ct) {
#pragma unroll
    for (int i = 0; i < 4; ++i) {
      float v = acc[ct][i] * dvv[i];
      float o = __shfl_xor(v, 1);   // partner col (all lanes participate)
      if (!(lane & 1) && rbase + i < n) {
        unsigned int p = (unsigned)f2bf(v) | ((unsigned)f2bf(o) << 16);
        XWb[(size_t)(rbase + i) * (DOUT / 2) + ct * 8 + ((lane & 15) >> 1)] = p;
      }
    }
  }
}

// pull-gather from bf16 y: h = bias + dinv[i]*( y_i + sum_e w_e * y_{row_e} )
// MODE 0: apply BN+ReLU, write packed bf16 hb.  MODE 1: D=64, L2-normalize, f32 d_out.
template<int D, int MODE>
__global__ __launch_bounds__(256) void gather_kernel(
    const int* __restrict__ rowptr, const int2* __restrict__ csr,
    const unsigned int* __restrict__ xwb, const float* __restrict__ dinv,
    const float* __restrict__ bias,
    const float* __restrict__ bnsc, const float* __restrict__ bnsh,
    void* __restrict__ outp, int n)
{
  int wid  = (blockIdx.x * blockDim.x + threadIdx.x) >> 6;
  int lane = threadIdx.x & 63;
  if (wid >= n) return;
  const int start = rowptr[wid];
  const int end   = rowptr[wid + 1];
  const float dv  = dinv[wid];

  if constexpr (MODE == 0) {
    // D=128: lane handles cols (2*lane, 2*lane+1) = uint index `lane`, ld=64 uints
    unsigned int su = xwb[(size_t)wid * 64 + lane];
    float a0 = bflo(su), a1 = bfhi(su);
    int e = start;
    for (; e + 3 < end; e += 4) {
      int2 p0 = csr[e], p1 = csr[e + 1], p2 = csr[e + 2], p3 = csr[e + 3];
      unsigned int u0 = xwb[(size_t)p0.x * 64 + lane];
      unsigned int u1 = xwb[(size_t)p1.x * 64 + lane];
      unsigned int u2 = xwb[(size_t)p2.x * 64 + lane];
      unsigned int u3 = xwb[(size_t)p3.x * 64 + lane];
      float n0 = __int_as_float(p0.y), n1 = __int_as_float(p1.y);
      float n2 = __int_as_float(p2.y), n3 = __int_as_float(p3.y);
      a0 = fmaf(bflo(u0), n0, a0); a1 = fmaf(bfhi(u0), n0, a1);
      a0 = fmaf(bflo(u1), n1, a0); a1 = fmaf(bfhi(u1), n1, a1);
      a0 = fmaf(bflo(u2), n2, a0); a1 = fmaf(bfhi(u2), n2, a1);
      a0 = fmaf(bflo(u3), n3, a0); a1 = fmaf(bfhi(u3), n3, a1);
    }
    for (; e < end; ++e) {
      int2 p0 = csr[e];
      unsigned int u0 = xwb[(size_t)p0.x * 64 + lane];
      float n0 = __int_as_float(p0.y);
      a0 = fmaf(bflo(u0), n0, a0); a1 = fmaf(bfhi(u0), n0, a1);
    }
    a0 = fmaf(dv, a0, bias[lane * 2]);
    a1 = fmaf(dv, a1, bias[lane * 2 + 1]);
    // fused BN + ReLU, pack bf16
    a0 = fmaxf(fmaf(a0, bnsc[lane * 2],     bnsh[lane * 2]),     0.f);
    a1 = fmaxf(fmaf(a1, bnsc[lane * 2 + 1], bnsh[lane * 2 + 1]), 0.f);
    ((unsigned int*)outp)[(size_t)wid * 64 + lane] =
        (unsigned)f2bf(a0) | ((unsigned)f2bf(a1) << 16);
  } else {
    // D=64, ld=32 uints: lane handles col `lane`; pairs of lanes share a uint
    const int ui = lane >> 1;
    unsigned int su = xwb[(size_t)wid * 32 + ui];
    float a = (lane & 1) ? bfhi(su) : bflo(su);
    int e = start;
    for (; e + 3 < end; e += 4) {
      int2 p0 = csr[e], p1 = csr[e + 1], p2 = csr[e + 2], p3 = csr[e + 3];
      unsigned int u0 = xwb[(size_t)p0.x * 32 + ui];
      unsigned int u1 = xwb[(size_t)p1.x * 32 + ui];
      unsigned int u2 = xwb[(size_t)p2.x * 32 + ui];
      unsigned int u3 = xwb[(size_t)p3.x * 32 + ui];
      float v0 = (lane & 1) ? bfhi(u0) : bflo(u0);
      float v1 = (lane & 1) ? bfhi(u1) : bflo(u1);
      float v2 = (lane & 1) ? bfhi(u2) : bflo(u2);
      float v3 = (lane & 1) ? bfhi(u3) : bflo(u3);
      a = fmaf(v0, __int_as_float(p0.y), a);
      a = fmaf(v1, __int_as_float(p1.y), a);
      a = fmaf(v2, __int_as_float(p2.y), a);
      a = fmaf(v3, __int_as_float(p3.y), a);
    }
    for (; e < end; ++e) {
      int2 p0 = csr[e];
      unsigned int u0 = xwb[(size_t)p0.x * 32 + ui];
      float v0 = (lane & 1) ? bfhi(u0) : bflo(u0);
      a = fmaf(v0, __int_as_float(p0.y), a);
    }
    a = fmaf(dv, a, bias[lane]);
    float s = a * a;
#pragma unroll
    for (int off = 32; off >= 1; off >>= 1) s += __shfl_xor(s, off);
    float scale = 1.0f / fmaxf(sqrtf(s), 1e-12f);
    ((float*)outp)[(size_t)wid * 64 + lane] = a * scale;
  }
}

extern "C" void kernel_launch(void* const* d_in, const int* in_sizes, int n_in,
                              void* d_out, int out_size, void* d_ws, size_t ws_size,
                              hipStream_t stream)
{
  const float* x   = (const float*)d_in[0];
  const int*   ei  = (const int*)d_in[1];
  const float* ew  = (const float*)d_in[2];
  const float* W1  = (const float*)d_in[3];
  const float* b1  = (const float*)d_in[4];
  const float* g1  = (const float*)d_in[5];
  const float* be1 = (const float*)d_in[6];
  const float* rm1 = (const float*)d_in[7];
  const float* rv1 = (const float*)d_in[8];
  const float* W2  = (const float*)d_in[9];
  const float* b2  = (const float*)d_in[10];
  const float* g2  = (const float*)d_in[11];
  const float* be2 = (const float*)d_in[12];
  const float* rm2 = (const float*)d_in[13];
  const float* rv2 = (const float*)d_in[14];
  const float* W3  = (const float*)d_in[15];
  const float* b3  = (const float*)d_in[16];

  const int N = in_sizes[0] / 128;
  const int E = in_sizes[2];
  const int* row = ei;       // edge_index[0]
  const int* col = ei + E;   // edge_index[1]

  const int nbk   = (N + 255) >> 8;                 // coarse buckets (col>>8)
  const int nblkA = (E + AB_CHUNK - 1) / AB_CHUNK;  // phase-A blocks
  const int L     = nbk * nblkA;                    // count-matrix length
  const int nb2   = (L + 1023) / 1024;              // scan partial blocks

  char* ws = (char*)d_ws;
  size_t off = 0;
  auto alloc = [&](size_t bytes) -> void* {
    void* p = ws + off;
    off += (bytes + 255) & ~(size_t)255;
    return p;
  };
  int*   cntmat = (int*)  alloc((size_t)L * 4);
  int*   scnt   = (int*)  alloc((size_t)(L + 1) * 4);
  int*   bsum   = (int*)  alloc((size_t)1024 * 4);
  int2*  bucketed = (int2*)alloc((size_t)E * 8);
  int2*  csr    = (int2*) alloc((size_t)E * 8);
  int*   rowptr = (int*)  alloc((size_t)(N + 1) * 4);
  float* dinv   = (float*)alloc((size_t)N * 4);
  float* sc1    = (float*)alloc(512);
  float* sh1    = (float*)alloc(512);
  float* sc2    = (float*)alloc(512);
  float* sh2    = (float*)alloc(512);
  unsigned short* Wt1 = (unsigned short*)alloc(128 * 128 * 2);
  unsigned short* Wt2 = (unsigned short*)alloc(128 * 128 * 2);
  unsigned short* Wt3 = (unsigned short*)alloc(64 * 128 * 2);
  unsigned int* xwb = (unsigned int*)alloc((size_t)N * 64 * 4);  // bf16-packed y
  unsigned int* hb  = (unsigned int*)alloc((size_t)N * 64 * 4);  // bf16-packed h (post BN+ReLU)

  // ---- weight transposes + BN prep (independent) ----
  wt_kernel<<<64, 256, 0, stream>>>(W1, Wt1, 128);
  wt_kernel<<<64, 256, 0, stream>>>(W2, Wt2, 128);
  wt_kernel<<<32, 256, 0, stream>>>(W3, Wt3, 64);
  bn_prep_kernel<<<1, 128, 0, stream>>>(g1, be1, rm1, rv1, g2, be2, rm2, rv2,
                                        sc1, sh1, sc2, sh2);

  // ---- CSR build (deterministic two-level bucket sort) ----
  histA<<<nblkA, 256, 0, stream>>>(col, cntmat, E, nbk, nblkA);
  scan_partial<<<nb2, 256, 0, stream>>>(cntmat, bsum, L);
  scan_bsum<<<1, 1024, 0, stream>>>(bsum, nb2, scnt, L);
  scan_apply<<<nb2, 256, 0, stream>>>(cntmat, bsum, scnt, L);
  scatA<<<nblkA, 256, 0, stream>>>(row, col, ew, scnt, bucketed, E, nbk, nblkA);
  bucketB<<<nbk, 256, 0, stream>>>(bucketed, scnt, csr, rowptr, dinv, E, N, nbk, nblkA);

  const int gGM = (N + 63) / 64;  // mfma gemm blocks (64 rows each)
  const int gW  = (N + 3) / 4;    // gather blocks (4 waves/block)

  // layer 1
  gemm_mfma<128, false><<<gGM, 256, 0, stream>>>(x, Wt1, dinv, xwb, N);
  gather_kernel<128, 0><<<gW, 256, 0, stream>>>(rowptr, csr, xwb, dinv, b1, sc1, sh1, hb, N);

  // layer 2
  gemm_mfma<128, true><<<gGM, 256, 0, stream>>>(hb, Wt2, dinv, xwb, N);
  gather_kernel<128, 0><<<gW, 256, 0, stream>>>(rowptr, csr, xwb, dinv, b2, sc2, sh2, hb, N);

  // layer 3 (DOUT=64) + fused L2 normalize -> d_out
  gemm_mfma<64, true><<<gGM, 256, 0, stream>>>(hb, Wt3, dinv, xwb, N);
  gather_kernel<64, 1><<<gW, 256, 0, stream>>>(rowptr, csr, xwb, dinv, b3, nullptr, nullptr,
                                               (float*)d_out, N);
}

// Round 7
// 330.224 us; speedup vs baseline: 21.1267x; 1.0827x over previous
//
#include <hip/hip_runtime.h>
#include <cstddef>

#define TPB 256
#define AB_CHUNK 4096   // edges per phase-A block

typedef __attribute__((ext_vector_type(8))) short short8;   // 8 bf16 (4 VGPRs)
typedef __attribute__((ext_vector_type(4))) float f32x4;    // MFMA C/D frag

__device__ inline unsigned short f2bf(float f) {  // RNE float->bf16
  unsigned int u = __float_as_uint(f);
  return (unsigned short)((u + 0x7fffu + ((u >> 16) & 1u)) >> 16);
}
__device__ inline float bflo(unsigned int u) { return __uint_as_float(u << 16); }
__device__ inline float bfhi(unsigned int u) { return __uint_as_float(u & 0xffff0000u); }

// ---- Phase A1: per-block coarse histogram (bucket = col>>8), LDS atomics only
__global__ __launch_bounds__(256) void histA(const int* __restrict__ col,
                                             int* __restrict__ cntmat,
                                             int E, int nbk, int nblkA) {
  __shared__ int hist[512];
  for (int i = threadIdx.x; i < nbk; i += 256) hist[i] = 0;
  __syncthreads();
  const int base = blockIdx.x * AB_CHUNK;
  const int lim  = min(base + AB_CHUNK, E);
  for (int i = base + threadIdx.x; i < lim; i += 256)
    atomicAdd(&hist[col[i] >> 8], 1);
  __syncthreads();
  for (int k = threadIdx.x; k < nbk; k += 256)
    cntmat[k * nblkA + blockIdx.x] = hist[k];   // bucket-major
}

// ---- hierarchical exclusive scan (arbitrary n; out[n] = total) ----
__global__ __launch_bounds__(256) void scan_partial(const int* __restrict__ cnt,
                                                    int* __restrict__ bsum, int n) {
  __shared__ int red[256];
  const int b = blockIdx.x, tid = threadIdx.x;
  const int base = b * 1024 + tid * 4;
  int s = 0;
  if (base + 3 < n) {
    int4 v = *(const int4*)(cnt + base);
    s = v.x + v.y + v.z + v.w;
  } else {
    for (int j = 0; j < 4; ++j) if (base + j < n) s += cnt[base + j];
  }
  red[tid] = s; __syncthreads();
  for (int off = 128; off >= 1; off >>= 1) {
    if (tid < off) red[tid] += red[tid + off];
    __syncthreads();
  }
  if (tid == 0) bsum[b] = red[0];
}

__global__ __launch_bounds__(1024) void scan_bsum(int* __restrict__ bsum, int nb,
                                                  int* __restrict__ out, int n) {
  __shared__ int sh[1024];
  const int tid = threadIdx.x;
  int v = (tid < nb) ? bsum[tid] : 0;
  sh[tid] = v; __syncthreads();
  for (int off = 1; off < 1024; off <<= 1) {
    int t = (tid >= off) ? sh[tid - off] : 0;
    __syncthreads();
    sh[tid] += t;
    __syncthreads();
  }
  if (tid < nb) bsum[tid] = sh[tid] - v;   // exclusive
  if (tid == 1023) out[n] = sh[1023];      // grand total
}

__global__ __launch_bounds__(256) void scan_apply(const int* __restrict__ cnt,
                                                  const int* __restrict__ bsum,
                                                  int* __restrict__ out, int n) {
  __shared__ int red[256];
  const int b = blockIdx.x, tid = threadIdx.x;
  const int base = b * 1024 + tid * 4;
  int v0 = 0, v1 = 0, v2 = 0, v3 = 0;
  if (base + 3 < n) {
    int4 v = *(const int4*)(cnt + base);
    v0 = v.x; v1 = v.y; v2 = v.z; v3 = v.w;
  } else {
    if (base     < n) v0 = cnt[base];
    if (base + 1 < n) v1 = cnt[base + 1];
    if (base + 2 < n) v2 = cnt[base + 2];
    if (base + 3 < n) v3 = cnt[base + 3];
  }
  const int t = v0 + v1 + v2 + v3;
  red[tid] = t; __syncthreads();
  for (int off = 1; off < 256; off <<= 1) {
    int x = (tid >= off) ? red[tid - off] : 0;
    __syncthreads();
    red[tid] += x;
    __syncthreads();
  }
  int excl = red[tid] - t + bsum[b];
  if (base     < n) out[base]     = excl;
  if (base + 1 < n) out[base + 1] = excl + v0;
  if (base + 2 < n) out[base + 2] = excl + v0 + v1;
  if (base + 3 < n) out[base + 3] = excl + v0 + v1 + v2;
}

// ---- Phase A3: scatter edges into bucket-contiguous order
// payload: {row | (col&255)<<17, w_bits}  (row < 2^17, col_local < 256)
__global__ __launch_bounds__(256) void scatA(const int* __restrict__ row,
                                             const int* __restrict__ col,
                                             const float* __restrict__ w,
                                             const int* __restrict__ scnt,
                                             int2* __restrict__ bucketed,
                                             int E, int nbk, int nblkA) {
  __shared__ int cur[512];
  for (int k = threadIdx.x; k < nbk; k += 256)
    cur[k] = scnt[k * nblkA + blockIdx.x];
  __syncthreads();
  const int base = blockIdx.x * AB_CHUNK;
  const int lim  = min(base + AB_CHUNK, E);
  for (int i = base + threadIdx.x; i < lim; i += 256) {
    int c = col[i];
    int pos = atomicAdd(&cur[c >> 8], 1);
    bucketed[pos] = make_int2(row[i] | ((c & 255) << 17), __float_as_int(w[i]));
  }
}

// ---- Phase B: per-bucket (256 nodes) local sort -> CSR + rowptr + dinv
__global__ __launch_bounds__(256) void bucketB(const int2* __restrict__ bucketed,
                                               const int* __restrict__ scnt,
                                               int2* __restrict__ csr,
                                               int* __restrict__ rowptr,
                                               float* __restrict__ dinv,
                                               int E, int N, int nbk, int nblkA) {
  __shared__ int   hist[256];   // then reused as cursor
  __shared__ float degf[256];
  __shared__ int   excl[256];
  const int b = blockIdx.x, tid = threadIdx.x;
  const int start = scnt[b * nblkA];
  const int end   = (b == nbk - 1) ? E : scnt[(b + 1) * nblkA];
  hist[tid] = 0; degf[tid] = 0.f;
  __syncthreads();
  for (int i = start + tid; i < end; i += 256) {
    int2 p = bucketed[i];
    int cl = (p.x >> 17) & 255;
    atomicAdd(&hist[cl], 1);
    atomicAdd(&degf[cl], __int_as_float(p.y));
  }
  __syncthreads();
  const int v = hist[tid];
  excl[tid] = v;
  __syncthreads();
  for (int off = 1; off < 256; off <<= 1) {
    int t = (tid >= off) ? excl[tid - off] : 0;
    __syncthreads();
    excl[tid] += t;
    __syncthreads();
  }
  const int ex = excl[tid] - v;  // exclusive prefix within bucket
  const int node = b * 256 + tid;
  if (node < N) {
    rowptr[node] = start + ex;
    dinv[node]   = rsqrtf(degf[tid] + 1.0f);   // +1 = self-loop
  }
  if (b == nbk - 1 && tid == 0) rowptr[N] = E;
  __syncthreads();
  hist[tid] = ex;       // reuse as running cursor
  __syncthreads();
  for (int i = start + tid; i < end; i += 256) {
    int2 p = bucketed[i];
    int cl = (p.x >> 17) & 255;
    int pos = start + atomicAdd(&hist[cl], 1);
    csr[pos] = make_int2(p.x & 0x1FFFF, p.y);   // {row, w}
  }
}

__global__ void bn_prep_kernel(const float* g1, const float* be1, const float* rm1, const float* rv1,
                               const float* g2, const float* be2, const float* rm2, const float* rv2,
                               float* sc1, float* sh1, float* sc2, float* sh2) {
  int t = threadIdx.x;
  if (t < 128) {
    float s1 = g1[t] * rsqrtf(rv1[t] + 1e-5f);
    sc1[t] = s1; sh1[t] = be1[t] - rm1[t] * s1;
    float s2 = g2[t] * rsqrtf(rv2[t] + 1e-5f);
    sc2[t] = s2; sh2[t] = be2[t] - rm2[t] * s2;
  }
}

// W[128,DOUT] f32 -> Wt[DOUT,128] bf16 (transposed)
__global__ void wt_kernel(const float* __restrict__ W, unsigned short* __restrict__ Wt, int DOUT) {
  int t = blockIdx.x * blockDim.x + threadIdx.x;   // t < DOUT*128
  int nidx = t >> 7, k = t & 127;
  Wt[t] = f2bf(W[(size_t)k * DOUT + nidx]);
}

// MFMA GEMM: Xbf[64-row tile] @ W -> y = dinv[r]*(X@W) packed bf16 (ld = DOUT/2 uints)
template<int DOUT, bool BF16IN>
__global__ __launch_bounds__(256) void gemm_mfma(
    const void* Xin,                         // f32[N,128] or packed-bf16 uint[N,64]
    const unsigned short* __restrict__ Wt,   // bf16 [DOUT][128]
    const float* __restrict__ dinv,
    unsigned int* __restrict__ XWb, int n)
{
  constexpr int CT = DOUT / 16;
  __shared__ unsigned short Xs[64][136];     // +8 pad: 2-way banks (free)
  __shared__ unsigned short Ws[DOUT][136];
  const int tid = threadIdx.x;
  const int r0  = blockIdx.x * 64;

  if constexpr (BF16IN) {
    const unsigned int* hb = (const unsigned int*)Xin;
    for (int i = tid; i < 64 * 16; i += 256) {           // uint4 = 8 bf16
      int rr = i >> 4, q = i & 15;
      uint4 v = make_uint4(0, 0, 0, 0);
      if (r0 + rr < n) v = *(const uint4*)(hb + (size_t)(r0 + rr) * 64 + q * 4);
      *(uint4*)(&Xs[rr][q * 8]) = v;
    }
  } else {
    const float* X = (const float*)Xin;
    for (int i = tid; i < 64 * 32; i += 256) {           // float4 -> 4 bf16
      int rr = i >> 5, q = i & 31;
      float4 v = make_float4(0.f, 0.f, 0.f, 0.f);
      if (r0 + rr < n) v = *(const float4*)(X + (size_t)(r0 + rr) * 128 + q * 4);
      uint2 p;
      p.x = (unsigned)f2bf(v.x) | ((unsigned)f2bf(v.y) << 16);
      p.y = (unsigned)f2bf(v.z) | ((unsigned)f2bf(v.w) << 16);
      *(uint2*)(&Xs[rr][q * 4]) = p;
    }
  }
  for (int i = tid; i < DOUT * 16; i += 256) {
    int nr = i >> 4, q = i & 15;
    *(uint4*)(&Ws[nr][q * 8]) = *(const uint4*)(Wt + (size_t)nr * 128 + q * 8);
  }
  __syncthreads();

  const int wid  = tid >> 6, lane = tid & 63;
  const int arow = wid * 16 + (lane & 15);
  const int koff = (lane >> 4) << 3;

  short8 af[4];
#pragma unroll
  for (int s = 0; s < 4; ++s)
    af[s] = *(const short8*)(&Xs[arow][s * 32 + koff]);

  f32x4 acc[CT];
#pragma unroll
  for (int ct = 0; ct < CT; ++ct) acc[ct] = (f32x4){0.f, 0.f, 0.f, 0.f};

#pragma unroll
  for (int ct = 0; ct < CT; ++ct) {
    const int brow = ct * 16 + (lane & 15);
#pragma unroll
    for (int s = 0; s < 4; ++s) {
      short8 bf = *(const short8*)(&Ws[brow][s * 32 + koff]);
      acc[ct] = __builtin_amdgcn_mfma_f32_16x16x32_bf16(af[s], bf, acc[ct], 0, 0, 0);
    }
  }

  const int rbase = r0 + wid * 16 + ((lane >> 4) << 2);
  float dvv[4];
#pragma unroll
  for (int i = 0; i < 4; ++i) dvv[i] = (rbase + i < n) ? dinv[rbase + i] : 0.f;

#pragma unroll
  for (int ct = 0; ct < CT; ++ct) {
#pragma unroll
    for (int i = 0; i < 4; ++i) {
      float v = acc[ct][i] * dvv[i];
      float o = __shfl_xor(v, 1);   // partner col
      if (!(lane & 1) && rbase + i < n) {
        unsigned int p = (unsigned)f2bf(v) | ((unsigned)f2bf(o) << 16);
        XWb[(size_t)(rbase + i) * (DOUT / 2) + ct * 8 + ((lane & 15) >> 1)] = p;
      }
    }
  }
}

// pull-gather from bf16 y: h = bias + dinv[i]*( y_i + sum_e w_e * y_{row_e} )
// MODE 0 (D=128): 2 edges/wave-iter (32 lanes x uint2 each), 8 edges in flight;
//                 BN+ReLU fused, writes packed bf16.
// MODE 1 (D=64):  4 edges/wave-iter (16 lanes x uint2 each), 16 edges in flight;
//                 L2-normalize fused, writes f32 d_out.
template<int MODE>
__global__ __launch_bounds__(256) void gather_kernel(
    const int* __restrict__ rowptr, const int2* __restrict__ csr,
    const unsigned int* __restrict__ xwb, const float* __restrict__ dinv,
    const float* __restrict__ bias,
    const float* __restrict__ bnsc, const float* __restrict__ bnsh,
    void* __restrict__ outp, int n)
{
  int wid  = (blockIdx.x * blockDim.x + threadIdx.x) >> 6;
  int lane = threadIdx.x & 63;
  if (wid >= n) return;
  const int start = rowptr[wid];
  const int end   = rowptr[wid + 1];
  const float dv  = dinv[wid];
  float a0 = 0.f, a1 = 0.f, a2 = 0.f, a3 = 0.f;

  if constexpr (MODE == 0) {
    const int li = lane & 31;   // uint2 index: features 4*li .. 4*li+3
    const int es = lane >> 5;   // edge slot (0/1)
    int e = start;
    for (; e + 7 < end; e += 8) {
      int2 p0 = csr[e     + es], p1 = csr[e + 2 + es];
      int2 p2 = csr[e + 4 + es], p3 = csr[e + 6 + es];
      uint2 u0 = ((const uint2*)(xwb + (size_t)p0.x * 64))[li];
      uint2 u1 = ((const uint2*)(xwb + (size_t)p1.x * 64))[li];
      uint2 u2 = ((const uint2*)(xwb + (size_t)p2.x * 64))[li];
      uint2 u3 = ((const uint2*)(xwb + (size_t)p3.x * 64))[li];
      float n0 = __int_as_float(p0.y), n1 = __int_as_float(p1.y);
      float n2 = __int_as_float(p2.y), n3 = __int_as_float(p3.y);
      a0 = fmaf(bflo(u0.x), n0, a0); a1 = fmaf(bfhi(u0.x), n0, a1);
      a2 = fmaf(bflo(u0.y), n0, a2); a3 = fmaf(bfhi(u0.y), n0, a3);
      a0 = fmaf(bflo(u1.x), n1, a0); a1 = fmaf(bfhi(u1.x), n1, a1);
      a2 = fmaf(bflo(u1.y), n1, a2); a3 = fmaf(bfhi(u1.y), n1, a3);
      a0 = fmaf(bflo(u2.x), n2, a0); a1 = fmaf(bfhi(u2.x), n2, a1);
      a2 = fmaf(bflo(u2.y), n2, a2); a3 = fmaf(bfhi(u2.y), n2, a3);
      a0 = fmaf(bflo(u3.x), n3, a0); a1 = fmaf(bfhi(u3.x), n3, a1);
      a2 = fmaf(bflo(u3.y), n3, a2); a3 = fmaf(bfhi(u3.y), n3, a3);
    }
    for (; e + 1 < end; e += 2) {
      int2 p0 = csr[e + es];
      uint2 u0 = ((const uint2*)(xwb + (size_t)p0.x * 64))[li];
      float n0 = __int_as_float(p0.y);
      a0 = fmaf(bflo(u0.x), n0, a0); a1 = fmaf(bfhi(u0.x), n0, a1);
      a2 = fmaf(bflo(u0.y), n0, a2); a3 = fmaf(bfhi(u0.y), n0, a3);
    }
    if (e < end) {
      int2 p0 = csr[e];
      uint2 u0 = ((const uint2*)(xwb + (size_t)p0.x * 64))[li];
      float n0 = (es == 0) ? __int_as_float(p0.y) : 0.f;
      a0 = fmaf(bflo(u0.x), n0, a0); a1 = fmaf(bfhi(u0.x), n0, a1);
      a2 = fmaf(bflo(u0.y), n0, a2); a3 = fmaf(bfhi(u0.y), n0, a3);
    }
    // reduce the two edge-halves
    a0 += __shfl_xor(a0, 32); a1 += __shfl_xor(a1, 32);
    a2 += __shfl_xor(a2, 32); a3 += __shfl_xor(a3, 32);
    // self + dinv + bias + BN + ReLU
    uint2 su = ((const uint2*)(xwb + (size_t)wid * 64))[li];
    a0 += bflo(su.x); a1 += bfhi(su.x); a2 += bflo(su.y); a3 += bfhi(su.y);
    const int f = li * 4;
    a0 = fmaf(dv, a0, bias[f]);     a1 = fmaf(dv, a1, bias[f + 1]);
    a2 = fmaf(dv, a2, bias[f + 2]); a3 = fmaf(dv, a3, bias[f + 3]);
    a0 = fmaxf(fmaf(a0, bnsc[f],     bnsh[f]),     0.f);
    a1 = fmaxf(fmaf(a1, bnsc[f + 1], bnsh[f + 1]), 0.f);
    a2 = fmaxf(fmaf(a2, bnsc[f + 2], bnsh[f + 2]), 0.f);
    a3 = fmaxf(fmaf(a3, bnsc[f + 3], bnsh[f + 3]), 0.f);
    if (lane < 32) {
      uint2 p;
      p.x = (unsigned)f2bf(a0) | ((unsigned)f2bf(a1) << 16);
      p.y = (unsigned)f2bf(a2) | ((unsigned)f2bf(a3) << 16);
      ((uint2*)outp)[(size_t)wid * 32 + li] = p;
    }
  } else {
    const int li = lane & 15;   // uint2 index: features 4*li .. 4*li+3
    const int es = lane >> 4;   // edge slot (0..3)
    int e = start;
    for (; e + 15 < end; e += 16) {
      int2 p0 = csr[e      + es], p1 = csr[e + 4  + es];
      int2 p2 = csr[e + 8  + es], p3 = csr[e + 12 + es];
      uint2 u0 = ((const uint2*)(xwb + (size_t)p0.x * 32))[li];
      uint2 u1 = ((const uint2*)(xwb + (size_t)p1.x * 32))[li];
      uint2 u2 = ((const uint2*)(xwb + (size_t)p2.x * 32))[li];
      uint2 u3 = ((const uint2*)(xwb + (size_t)p3.x * 32))[li];
      float n0 = __int_as_float(p0.y), n1 = __int_as_float(p1.y);
      float n2 = __int_as_float(p2.y), n3 = __int_as_float(p3.y);
      a0 = fmaf(bflo(u0.x), n0, a0); a1 = fmaf(bfhi(u0.x), n0, a1);
      a2 = fmaf(bflo(u0.y), n0, a2); a3 = fmaf(bfhi(u0.y), n0, a3);
      a0 = fmaf(bflo(u1.x), n1, a0); a1 = fmaf(bfhi(u1.x), n1, a1);
      a2 = fmaf(bflo(u1.y), n1, a2); a3 = fmaf(bfhi(u1.y), n1, a3);
      a0 = fmaf(bflo(u2.x), n2, a0); a1 = fmaf(bfhi(u2.x), n2, a1);
      a2 = fmaf(bflo(u2.y), n2, a2); a3 = fmaf(bfhi(u2.y), n2, a3);
      a0 = fmaf(bflo(u3.x), n3, a0); a1 = fmaf(bfhi(u3.x), n3, a1);
      a2 = fmaf(bflo(u3.y), n3, a2); a3 = fmaf(bfhi(u3.y), n3, a3);
    }
    for (; e + 3 < end; e += 4) {
      int2 p0 = csr[e + es];
      uint2 u0 = ((const uint2*)(xwb + (size_t)p0.x * 32))[li];
      float n0 = __int_as_float(p0.y);
      a0 = fmaf(bflo(u0.x), n0, a0); a1 = fmaf(bfhi(u0.x), n0, a1);
      a2 = fmaf(bflo(u0.y), n0, a2); a3 = fmaf(bfhi(u0.y), n0, a3);
    }
    for (; e < end; ++e) {
      int2 p0 = csr[e];
      uint2 u0 = ((const uint2*)(xwb + (size_t)p0.x * 32))[li];
      float n0 = (es == 0) ? __int_as_float(p0.y) : 0.f;
      a0 = fmaf(bflo(u0.x), n0, a0); a1 = fmaf(bfhi(u0.x), n0, a1);
      a2 = fmaf(bflo(u0.y), n0, a2); a3 = fmaf(bfhi(u0.y), n0, a3);
    }
    // reduce the four edge-quadrants
    a0 += __shfl_xor(a0, 16); a1 += __shfl_xor(a1, 16);
    a2 += __shfl_xor(a2, 16); a3 += __shfl_xor(a3, 16);
    a0 += __shfl_xor(a0, 32); a1 += __shfl_xor(a1, 32);
    a2 += __shfl_xor(a2, 32); a3 += __shfl_xor(a3, 32);
    // self + dinv + bias
    uint2 su = ((const uint2*)(xwb + (size_t)wid * 32))[li];
    a0 += bflo(su.x); a1 += bfhi(su.x); a2 += bflo(su.y); a3 += bfhi(su.y);
    const int f = li * 4;
    a0 = fmaf(dv, a0, bias[f]);     a1 = fmaf(dv, a1, bias[f + 1]);
    a2 = fmaf(dv, a2, bias[f + 2]); a3 = fmaf(dv, a3, bias[f + 3]);
    // L2 norm across the 16-lane group (each group holds all 64 features)
    float s = a0 * a0 + a1 * a1 + a2 * a2 + a3 * a3;
#pragma unroll
    for (int off = 8; off >= 1; off >>= 1) s += __shfl_xor(s, off);
    float scale = 1.0f / fmaxf(sqrtf(s), 1e-12f);
    if (lane < 16) {
      float4 o = make_float4(a0 * scale, a1 * scale, a2 * scale, a3 * scale);
      *(float4*)((float*)outp + (size_t)wid * 64 + f) = o;
    }
  }
}

extern "C" void kernel_launch(void* const* d_in, const int* in_sizes, int n_in,
                              void* d_out, int out_size, void* d_ws, size_t ws_size,
                              hipStream_t stream)
{
  const float* x   = (const float*)d_in[0];
  const int*   ei  = (const int*)d_in[1];
  const float* ew  = (const float*)d_in[2];
  const float* W1  = (const float*)d_in[3];
  const float* b1  = (const float*)d_in[4];
  const float* g1  = (const float*)d_in[5];
  const float* be1 = (const float*)d_in[6];
  const float* rm1 = (const float*)d_in[7];
  const float* rv1 = (const float*)d_in[8];
  const float* W2  = (const float*)d_in[9];
  const float* b2  = (const float*)d_in[10];
  const float* g2  = (const float*)d_in[11];
  const float* be2 = (const float*)d_in[12];
  const float* rm2 = (const float*)d_in[13];
  const float* rv2 = (const float*)d_in[14];
  const float* W3  = (const float*)d_in[15];
  const float* b3  = (const float*)d_in[16];

  const int N = in_sizes[0] / 128;
  const int E = in_sizes[2];
  const int* row = ei;       // edge_index[0]
  const int* col = ei + E;   // edge_index[1]

  const int nbk   = (N + 255) >> 8;                 // coarse buckets (col>>8)
  const int nblkA = (E + AB_CHUNK - 1) / AB_CHUNK;  // phase-A blocks
  const int L     = nbk * nblkA;                    // count-matrix length
  const int nb2   = (L + 1023) / 1024;              // scan partial blocks

  char* ws = (char*)d_ws;
  size_t off = 0;
  auto alloc = [&](size_t bytes) -> void* {
    void* p = ws + off;
    off += (bytes + 255) & ~(size_t)255;
    return p;
  };
  int*   cntmat = (int*)  alloc((size_t)L * 4);
  int*   scnt   = (int*)  alloc((size_t)(L + 1) * 4);
  int*   bsum   = (int*)  alloc((size_t)1024 * 4);
  int2*  bucketed = (int2*)alloc((size_t)E * 8);
  int2*  csr    = (int2*) alloc((size_t)E * 8);
  int*   rowptr = (int*)  alloc((size_t)(N + 1) * 4);
  float* dinv   = (float*)alloc((size_t)N * 4);
  float* sc1    = (float*)alloc(512);
  float* sh1    = (float*)alloc(512);
  float* sc2    = (float*)alloc(512);
  float* sh2    = (float*)alloc(512);
  unsigned short* Wt1 = (unsigned short*)alloc(128 * 128 * 2);
  unsigned short* Wt2 = (unsigned short*)alloc(128 * 128 * 2);
  unsigned short* Wt3 = (unsigned short*)alloc(64 * 128 * 2);
  unsigned int* xwb = (unsigned int*)alloc((size_t)N * 64 * 4);  // bf16-packed y
  unsigned int* hb  = (unsigned int*)alloc((size_t)N * 64 * 4);  // bf16-packed h

  // ---- weight transposes + BN prep ----
  wt_kernel<<<64, 256, 0, stream>>>(W1, Wt1, 128);
  wt_kernel<<<64, 256, 0, stream>>>(W2, Wt2, 128);
  wt_kernel<<<32, 256, 0, stream>>>(W3, Wt3, 64);
  bn_prep_kernel<<<1, 128, 0, stream>>>(g1, be1, rm1, rv1, g2, be2, rm2, rv2,
                                        sc1, sh1, sc2, sh2);

  // ---- CSR build (deterministic two-level bucket sort) ----
  histA<<<nblkA, 256, 0, stream>>>(col, cntmat, E, nbk, nblkA);
  scan_partial<<<nb2, 256, 0, stream>>>(cntmat, bsum, L);
  scan_bsum<<<1, 1024, 0, stream>>>(bsum, nb2, scnt, L);
  scan_apply<<<nb2, 256, 0, stream>>>(cntmat, bsum, scnt, L);
  scatA<<<nblkA, 256, 0, stream>>>(row, col, ew, scnt, bucketed, E, nbk, nblkA);
  bucketB<<<nbk, 256, 0, stream>>>(bucketed, scnt, csr, rowptr, dinv, E, N, nbk, nblkA);

  const int gGM = (N + 63) / 64;  // mfma gemm blocks (64 rows each)
  const int gW  = (N + 3) / 4;    // gather blocks (4 waves/block)

  // layer 1
  gemm_mfma<128, false><<<gGM, 256, 0, stream>>>(x, Wt1, dinv, xwb, N);
  gather_kernel<0><<<gW, 256, 0, stream>>>(rowptr, csr, xwb, dinv, b1, sc1, sh1, hb, N);

  // layer 2
  gemm_mfma<128, true><<<gGM, 256, 0, stream>>>(hb, Wt2, dinv, xwb, N);
  gather_kernel<0><<<gW, 256, 0, stream>>>(rowptr, csr, xwb, dinv, b2, sc2, sh2, hb, N);

  // layer 3 (DOUT=64) + fused L2 normalize -> d_out
  gemm_mfma<64, true><<<gGM, 256, 0, stream>>>(hb, Wt3, dinv, xwb, N);
  gather_kernel<1><<<gW, 256, 0, stream>>>(rowptr, csr, xwb, dinv, b3, nullptr, nullptr,
                                           (float*)d_out, N);
}